// Round 2
// baseline (4646.457 us; speedup 1.0000x reference)
//
#include <hip/hip_runtime.h>
#include <hip/hip_bf16.h>

// Problem constants (Qwen3.5-VL vision attention)
constexpr int N_TOK  = 2048;
constexpr int DIM    = 1280;
constexpr int NHEAD  = 16;
constexpr int HD     = 80;
constexpr int QKV_N  = 3 * DIM;   // 3840

// Runtime-dtype load: BF=1 -> buffer is bf16, BF=0 -> fp32.
template <int BF>
__device__ __forceinline__ float ldf(const void* p, size_t i) {
  if constexpr (BF) return __bfloat162float(((const __hip_bfloat16*)p)[i]);
  else              return ((const float*)p)[i];
}

// ---------------------------------------------------------------------------
// Dtype probe: read first `nwords` fp32 words of a float-family input buffer.
// fp32-actual data: all |x| < ~10. bf16-actual data read as fp32: the high
// bf16's exponent/mantissa bits land in the fp32 exponent field -> |x| ~ 1e35
// (or inf/NaN) for essentially every nonzero word.
// ---------------------------------------------------------------------------
__global__ void detect_kernel(const void* w, int nwords, int* flag) {
  __shared__ int cnt;
  if (threadIdx.x == 0) cnt = 0;
  __syncthreads();
  const float* f = (const float*)w;
  int c = 0;
  for (int i = threadIdx.x; i < nwords; i += blockDim.x) {
    float x = f[i];
    if (!(fabsf(x) < 1e20f)) c++;  // counts huge, inf, and NaN
  }
  atomicAdd(&cnt, c);
  __syncthreads();
  if (threadIdx.x == 0) *flag = (cnt > nwords / 64) ? 1 : 0;
}

// ---------------------------------------------------------------------------
// Generic tiled GEMM: C[M,N] = A[M,K] @ B[K,N] + bias[N]
// 64x64 tile, 256 threads, 4x4 micro-tile per thread, fp32 accumulate.
// ABF/WBF: dtype of A / (B,bias). OBF: output dtype.
// ---------------------------------------------------------------------------
template <int ABF, int WBF, int OBF>
__device__ void gemm_body(const void* __restrict__ A, const void* __restrict__ B,
                          const void* __restrict__ bias, void* __restrict__ C,
                          int M, int N, int K) {
  constexpr int TILE = 64, BK = 16;
  __shared__ float As[BK][TILE + 1];
  __shared__ float Bs[BK][TILE + 1];
  const int tid = threadIdx.x;
  const int tx = tid & 15, ty = tid >> 4;
  const int row0 = blockIdx.y * TILE, col0 = blockIdx.x * TILE;
  float acc[4][4] = {};

  for (int k0 = 0; k0 < K; k0 += BK) {
    for (int i = tid; i < TILE * BK; i += 256) {
      int m = i >> 4, kk = i & 15;
      As[kk][m] = ldf<ABF>(A, (size_t)(row0 + m) * K + k0 + kk);
    }
    for (int i = tid; i < TILE * BK; i += 256) {
      int kk = i >> 6, n = i & 63;
      Bs[kk][n] = ldf<WBF>(B, (size_t)(k0 + kk) * N + col0 + n);
    }
    __syncthreads();
#pragma unroll
    for (int kk = 0; kk < BK; ++kk) {
      float a[4], b[4];
#pragma unroll
      for (int i = 0; i < 4; ++i) a[i] = As[kk][ty * 4 + i];
#pragma unroll
      for (int j = 0; j < 4; ++j) b[j] = Bs[kk][tx * 4 + j];
#pragma unroll
      for (int i = 0; i < 4; ++i)
#pragma unroll
        for (int j = 0; j < 4; ++j) acc[i][j] += a[i] * b[j];
    }
    __syncthreads();
  }

#pragma unroll
  for (int i = 0; i < 4; ++i) {
    int r = row0 + ty * 4 + i;
#pragma unroll
    for (int j = 0; j < 4; ++j) {
      int c = col0 + tx * 4 + j;
      float v = acc[i][j] + ldf<WBF>(bias, c);
      size_t idx = (size_t)r * N + c;
      if constexpr (OBF) ((__hip_bfloat16*)C)[idx] = __float2bfloat16(v);
      else               ((float*)C)[idx] = v;
    }
  }
}

// GEMM1: A = hidden_states (dtype=flag), B = Wqkv (flag), out fp32 workspace.
__global__ void gemm1_kernel(const void* A, const void* B, const void* bias,
                             void* C, int M, int N, int K, const int* flagp) {
  if (*flagp) gemm_body<1, 1, 0>(A, B, bias, C, M, N, K);
  else        gemm_body<0, 0, 0>(A, B, bias, C, M, N, K);
}

// GEMM2: A = attn_out (fp32), B = Wproj (flag), out = d_out (dtype=flag).
__global__ void gemm2_kernel(const void* A, const void* B, const void* bias,
                             void* C, int M, int N, int K, const int* flagp) {
  if (*flagp) gemm_body<0, 1, 1>(A, B, bias, C, M, N, K);
  else        gemm_body<0, 0, 0>(A, B, bias, C, M, N, K);
}

// ---------------------------------------------------------------------------
// RoPE on q and k (in-place on fp32 qkv workspace).
// ---------------------------------------------------------------------------
template <int BF>
__device__ void rope_body(float* __restrict__ qkv, const void* __restrict__ cosb,
                          const void* __restrict__ sinb) {
  constexpr int HALF = HD / 2;  // 40
  int idx = blockIdx.x * blockDim.x + threadIdx.x;  // over N*2*H*40
  int n     = idx / (2 * NHEAD * HALF);
  int rem   = idx % (2 * NHEAD * HALF);
  int which = rem / (NHEAD * HALF);       // 0=q, 1=k
  int rem2  = rem % (NHEAD * HALF);
  int h     = rem2 / HALF;
  int d     = rem2 % HALF;
  size_t base = (size_t)n * QKV_N + which * DIM + h * HD;
  float x1 = qkv[base + d], x2 = qkv[base + d + HALF];
  float c1 = ldf<BF>(cosb, n * HD + d), c2 = ldf<BF>(cosb, n * HD + d + HALF);
  float s1 = ldf<BF>(sinb, n * HD + d), s2 = ldf<BF>(sinb, n * HD + d + HALF);
  qkv[base + d]        = x1 * c1 - x2 * s1;
  qkv[base + d + HALF] = x2 * c2 + x1 * s2;
}

__global__ void rope_kernel(float* qkv, const void* cosb, const void* sinb,
                            const int* flagp) {
  if (*flagp) rope_body<1>(qkv, cosb, sinb);
  else        rope_body<0>(qkv, cosb, sinb);
}

// ---------------------------------------------------------------------------
// Flash-style segment-masked attention (all fp32). One thread = one query.
// ---------------------------------------------------------------------------
__global__ void attn_kernel(const float* __restrict__ qkv,
                            const int* __restrict__ cu,
                            float* __restrict__ out) {
  constexpr int KC = 64;
  __shared__ __align__(16) float Ks[KC * HD];
  __shared__ __align__(16) float Vs[KC * HD];
  const int h = blockIdx.z, seg = blockIdx.y;
  const int s0 = cu[seg], s1 = cu[seg + 1];
  if (s0 + (int)blockIdx.x * 64 >= s1) return;  // uniform early-exit
  const int qi = s0 + blockIdx.x * 64 + (int)threadIdx.x;
  const bool active = qi < s1;
  const float scale = 0.11180339887498949f;  // 80^-0.5

  float4 q4[HD / 4];
  float acc[HD];
  float m = -1e30f, l = 0.f;
#pragma unroll
  for (int t = 0; t < HD; ++t) acc[t] = 0.f;
  if (active) {
    const float4* qp = reinterpret_cast<const float4*>(qkv + (size_t)qi * QKV_N + h * HD);
#pragma unroll
    for (int t = 0; t < HD / 4; ++t) {
      q4[t] = qp[t];
      q4[t].x *= scale; q4[t].y *= scale; q4[t].z *= scale; q4[t].w *= scale;
    }
  }

  for (int k0 = s0; k0 < s1; k0 += KC) {
    const int nk = min(KC, s1 - k0);
    __syncthreads();
    for (int i = (int)threadIdx.x; i < nk * (HD / 4); i += 64) {
      int r = i / (HD / 4), t = i % (HD / 4);
      reinterpret_cast<float4*>(Ks)[r * (HD / 4) + t] =
          reinterpret_cast<const float4*>(qkv + (size_t)(k0 + r) * QKV_N + DIM + h * HD)[t];
      reinterpret_cast<float4*>(Vs)[r * (HD / 4) + t] =
          reinterpret_cast<const float4*>(qkv + (size_t)(k0 + r) * QKV_N + 2 * DIM + h * HD)[t];
    }
    __syncthreads();
    if (active) {
      for (int j = 0; j < nk; ++j) {
        const float4* kp = reinterpret_cast<const float4*>(Ks + j * HD);
        float s = 0.f;
#pragma unroll
        for (int t = 0; t < HD / 4; ++t) {
          float4 kf = kp[t];
          s += q4[t].x * kf.x + q4[t].y * kf.y + q4[t].z * kf.z + q4[t].w * kf.w;
        }
        if (s > m) {
          float f = __expf(m - s);
          l *= f;
#pragma unroll
          for (int t = 0; t < HD; ++t) acc[t] *= f;
          m = s;
        }
        float p = __expf(s - m);
        l += p;
        const float* vp = Vs + j * HD;
#pragma unroll
        for (int t = 0; t < HD; ++t) acc[t] += p * vp[t];
      }
    }
  }

  if (active) {
    float inv = 1.f / l;
    float* op = out + (size_t)qi * DIM + h * HD;
#pragma unroll
    for (int t = 0; t < HD; ++t) op[t] = acc[t] * inv;
  }
}

// ---------------------------------------------------------------------------
extern "C" void kernel_launch(void* const* d_in, const int* in_sizes, int n_in,
                              void* d_out, int out_size, void* d_ws, size_t ws_size,
                              hipStream_t stream) {
  const void* hs    = d_in[0];
  const int*  cu    = (const int*)d_in[1];
  const void* cosb  = d_in[2];
  const void* sinb  = d_in[3];
  const void* Wqkv  = d_in[4];
  const void* bqkv  = d_in[5];
  const void* Wproj = d_in[6];
  const void* bproj = d_in[7];

  // workspace layout: qkv fp32 (31.5 MB) | attn_out fp32 (10.5 MB) | flag
  float* qkv      = (float*)d_ws;
  float* attn_out = qkv + (size_t)N_TOK * QKV_N;
  int*   flagp    = (int*)(attn_out + (size_t)N_TOK * DIM);

  // 0) detect float dtype of the float-family inputs (fp32 vs bf16)
  detect_kernel<<<1, 256, 0, stream>>>(Wqkv, 4096, flagp);

  // 1) qkv = hs @ Wqkv + bqkv   (2048x1280 @ 1280x3840), fp32 out
  gemm1_kernel<<<dim3(QKV_N / 64, N_TOK / 64), 256, 0, stream>>>(
      hs, Wqkv, bqkv, qkv, N_TOK, QKV_N, DIM, flagp);

  // 2) RoPE on q,k
  rope_kernel<<<(N_TOK * 2 * NHEAD * (HD / 2)) / 256, 256, 0, stream>>>(
      qkv, cosb, sinb, flagp);

  // 3) segment-masked attention
  int nseg = in_sizes[1] - 1;
  attn_kernel<<<dim3((N_TOK + 63) / 64, nseg, NHEAD), 64, 0, stream>>>(qkv, cu, attn_out);

  // 4) out = attn_out @ Wproj + bproj   (2048x1280 @ 1280x1280), dtype per flag
  gemm2_kernel<<<dim3(DIM / 64, N_TOK / 64), 256, 0, stream>>>(
      attn_out, Wproj, bproj, d_out, N_TOK, DIM, DIM, flagp);
}

// Round 3
// 1369.948 us; speedup vs baseline: 3.3917x; 3.3917x over previous
//
#include <hip/hip_runtime.h>
#include <hip/hip_bf16.h>

// Problem constants (Qwen3.5-VL vision attention)
constexpr int N_TOK  = 2048;
constexpr int DIM    = 1280;
constexpr int NHEAD  = 16;
constexpr int HD     = 80;
constexpr int QKV_N  = 3 * DIM;   // 3840

// Runtime-dtype load: BF=1 -> buffer is bf16, BF=0 -> fp32.
template <int BF>
__device__ __forceinline__ float ldf(const void* p, size_t i) {
  if constexpr (BF) return __bfloat162float(((const __hip_bfloat16*)p)[i]);
  else              return ((const float*)p)[i];
}

// ---------------------------------------------------------------------------
// Dtype probe (kept from R2 — resolved to fp32, costs ~3 us, keeps us safe).
// ---------------------------------------------------------------------------
__global__ void detect_kernel(const void* w, int nwords, int* flag) {
  __shared__ int cnt;
  if (threadIdx.x == 0) cnt = 0;
  __syncthreads();
  const float* f = (const float*)w;
  int c = 0;
  for (int i = threadIdx.x; i < nwords; i += blockDim.x) {
    float x = f[i];
    if (!(fabsf(x) < 1e20f)) c++;  // counts huge, inf, and NaN
  }
  atomicAdd(&cnt, c);
  __syncthreads();
  if (threadIdx.x == 0) *flag = (cnt > nwords / 64) ? 1 : 0;
}

// ---------------------------------------------------------------------------
// Generic tiled GEMM: C[M,N] = A[M,K] @ B[K,N] + bias[N]
// 64x64 tile, 256 threads, 4x4 micro-tile per thread, fp32 accumulate.
// ---------------------------------------------------------------------------
template <int ABF, int WBF, int OBF>
__device__ void gemm_body(const void* __restrict__ A, const void* __restrict__ B,
                          const void* __restrict__ bias, void* __restrict__ C,
                          int M, int N, int K) {
  constexpr int TILE = 64, BK = 16;
  __shared__ float As[BK][TILE + 1];
  __shared__ float Bs[BK][TILE + 1];
  const int tid = threadIdx.x;
  const int tx = tid & 15, ty = tid >> 4;
  const int row0 = blockIdx.y * TILE, col0 = blockIdx.x * TILE;
  float acc[4][4] = {};

  for (int k0 = 0; k0 < K; k0 += BK) {
    for (int i = tid; i < TILE * BK; i += 256) {
      int m = i >> 4, kk = i & 15;
      As[kk][m] = ldf<ABF>(A, (size_t)(row0 + m) * K + k0 + kk);
    }
    for (int i = tid; i < TILE * BK; i += 256) {
      int kk = i >> 6, n = i & 63;
      Bs[kk][n] = ldf<WBF>(B, (size_t)(k0 + kk) * N + col0 + n);
    }
    __syncthreads();
#pragma unroll
    for (int kk = 0; kk < BK; ++kk) {
      float a[4], b[4];
#pragma unroll
      for (int i = 0; i < 4; ++i) a[i] = As[kk][ty * 4 + i];
#pragma unroll
      for (int j = 0; j < 4; ++j) b[j] = Bs[kk][tx * 4 + j];
#pragma unroll
      for (int i = 0; i < 4; ++i)
#pragma unroll
        for (int j = 0; j < 4; ++j) acc[i][j] += a[i] * b[j];
    }
    __syncthreads();
  }

#pragma unroll
  for (int i = 0; i < 4; ++i) {
    int r = row0 + ty * 4 + i;
#pragma unroll
    for (int j = 0; j < 4; ++j) {
      int c = col0 + tx * 4 + j;
      float v = acc[i][j] + ldf<WBF>(bias, c);
      size_t idx = (size_t)r * N + c;
      if constexpr (OBF) ((__hip_bfloat16*)C)[idx] = __float2bfloat16(v);
      else               ((float*)C)[idx] = v;
    }
  }
}

__global__ void gemm1_kernel(const void* A, const void* B, const void* bias,
                             void* C, int M, int N, int K, const int* flagp) {
  if (*flagp) gemm_body<1, 1, 0>(A, B, bias, C, M, N, K);
  else        gemm_body<0, 0, 0>(A, B, bias, C, M, N, K);
}

__global__ void gemm2_kernel(const void* A, const void* B, const void* bias,
                             void* C, int M, int N, int K, const int* flagp) {
  if (*flagp) gemm_body<0, 1, 1>(A, B, bias, C, M, N, K);
  else        gemm_body<0, 0, 0>(A, B, bias, C, M, N, K);
}

// ---------------------------------------------------------------------------
// RoPE on q and k (in-place on fp32 qkv workspace).
// ---------------------------------------------------------------------------
template <int BF>
__device__ void rope_body(float* __restrict__ qkv, const void* __restrict__ cosb,
                          const void* __restrict__ sinb) {
  constexpr int HALF = HD / 2;  // 40
  int idx = blockIdx.x * blockDim.x + threadIdx.x;
  int n     = idx / (2 * NHEAD * HALF);
  int rem   = idx % (2 * NHEAD * HALF);
  int which = rem / (NHEAD * HALF);
  int rem2  = rem % (NHEAD * HALF);
  int h     = rem2 / HALF;
  int d     = rem2 % HALF;
  size_t base = (size_t)n * QKV_N + which * DIM + h * HD;
  float x1 = qkv[base + d], x2 = qkv[base + d + HALF];
  float c1 = ldf<BF>(cosb, n * HD + d), c2 = ldf<BF>(cosb, n * HD + d + HALF);
  float s1 = ldf<BF>(sinb, n * HD + d), s2 = ldf<BF>(sinb, n * HD + d + HALF);
  qkv[base + d]        = x1 * c1 - x2 * s1;
  qkv[base + d + HALF] = x2 * c2 + x1 * s2;
}

__global__ void rope_kernel(float* qkv, const void* cosb, const void* sinb,
                            const int* flagp) {
  if (*flagp) rope_body<1>(qkv, cosb, sinb);
  else        rope_body<0>(qkv, cosb, sinb);
}

// ---------------------------------------------------------------------------
// Flash-style segment-masked attention, v2 (spill-free decomposition).
// Block = 256 threads (4 waves) = one 64-query tile of one (head, segment).
// Lane owns (query, d-quarter): q_local = lane>>2, quarter = lane&3.
//   acc[20] + q[20] in registers (~60 VGPR, no scratch).
// Score: 20-FMA partial dot, then shfl_xor(1)+shfl_xor(2) across the 4-lane
// group. Online softmax replicated per group (branchless, exact when max
// doesn't grow since exp(0)==1).
// K/V chunks (64 x 80 fp32 each, 40 KB) staged in LDS via float4; inner-loop
// reads are same-address across the 16 query-groups -> LDS broadcast, no
// bank conflicts.
// ---------------------------------------------------------------------------
__global__ __launch_bounds__(256)
void attn_kernel(const float* __restrict__ qkv, const int* __restrict__ cu,
                 float* __restrict__ out) {
  constexpr int KC = 64;          // keys per LDS chunk
  constexpr int QT = 20;          // head-dim quarter
  __shared__ __align__(16) float Ks[KC * HD];
  __shared__ __align__(16) float Vs[KC * HD];

  const int h = blockIdx.z, seg = blockIdx.y;
  const int s0 = cu[seg], s1 = cu[seg + 1];
  if (s0 + (int)blockIdx.x * 64 >= s1) return;  // uniform early-exit

  const int tid   = threadIdx.x;
  const int wave  = tid >> 6;
  const int lane  = tid & 63;
  const int qloc  = lane >> 2;          // 0..15 within wave
  const int qt    = lane & 3;           // d-quarter 0..3
  const int qi    = s0 + blockIdx.x * 64 + wave * 16 + qloc;
  const bool active = qi < s1;
  const float scale = 0.11180339887498949f;  // 80^-0.5

  float4 q4[QT / 4];
  float  acc[QT];
  float  m = -1e30f, l = 0.f;
#pragma unroll
  for (int t = 0; t < QT; ++t) acc[t] = 0.f;
#pragma unroll
  for (int t = 0; t < QT / 4; ++t) q4[t] = make_float4(0.f, 0.f, 0.f, 0.f);
  if (active) {
    const float4* qp =
        reinterpret_cast<const float4*>(qkv + (size_t)qi * QKV_N + h * HD + qt * QT);
#pragma unroll
    for (int t = 0; t < QT / 4; ++t) {
      q4[t] = qp[t];
      q4[t].x *= scale; q4[t].y *= scale; q4[t].z *= scale; q4[t].w *= scale;
    }
  }

  for (int k0 = s0; k0 < s1; k0 += KC) {
    const int nk = min(KC, s1 - k0);
    __syncthreads();
    // stage K and V chunks: nk rows x 20 float4 each, coalesced-ish
    for (int i = tid; i < nk * (HD / 4); i += 256) {
      int r = i / (HD / 4), t = i % (HD / 4);
      reinterpret_cast<float4*>(Ks)[r * (HD / 4) + t] =
          reinterpret_cast<const float4*>(qkv + (size_t)(k0 + r) * QKV_N + DIM + h * HD)[t];
      reinterpret_cast<float4*>(Vs)[r * (HD / 4) + t] =
          reinterpret_cast<const float4*>(qkv + (size_t)(k0 + r) * QKV_N + 2 * DIM + h * HD)[t];
    }
    __syncthreads();

    for (int j = 0; j < nk; ++j) {
      const float4* kp = reinterpret_cast<const float4*>(Ks + j * HD + qt * QT);
      float s = 0.f;
#pragma unroll
      for (int t = 0; t < QT / 4; ++t) {
        float4 kf = kp[t];
        s += q4[t].x * kf.x + q4[t].y * kf.y + q4[t].z * kf.z + q4[t].w * kf.w;
      }
      // full score across the 4-lane group
      s += __shfl_xor(s, 1);
      s += __shfl_xor(s, 2);
      // branchless online softmax (f==1.0 exactly when max unchanged)
      float mn = fmaxf(m, s);
      float f  = __expf(m - mn);
      float p  = __expf(s - mn);
      m = mn;
      l = l * f + p;
      const float4* vp = reinterpret_cast<const float4*>(Vs + j * HD + qt * QT);
#pragma unroll
      for (int t = 0; t < QT / 4; ++t) {
        float4 vf = vp[t];
        acc[t * 4 + 0] = acc[t * 4 + 0] * f + p * vf.x;
        acc[t * 4 + 1] = acc[t * 4 + 1] * f + p * vf.y;
        acc[t * 4 + 2] = acc[t * 4 + 2] * f + p * vf.z;
        acc[t * 4 + 3] = acc[t * 4 + 3] * f + p * vf.w;
      }
    }
  }

  if (active) {
    float inv = 1.f / l;
    float4* op = reinterpret_cast<float4*>(out + (size_t)qi * DIM + h * HD + qt * QT);
#pragma unroll
    for (int t = 0; t < QT / 4; ++t) {
      op[t] = make_float4(acc[t * 4 + 0] * inv, acc[t * 4 + 1] * inv,
                          acc[t * 4 + 2] * inv, acc[t * 4 + 3] * inv);
    }
  }
}

// ---------------------------------------------------------------------------
extern "C" void kernel_launch(void* const* d_in, const int* in_sizes, int n_in,
                              void* d_out, int out_size, void* d_ws, size_t ws_size,
                              hipStream_t stream) {
  const void* hs    = d_in[0];
  const int*  cu    = (const int*)d_in[1];
  const void* cosb  = d_in[2];
  const void* sinb  = d_in[3];
  const void* Wqkv  = d_in[4];
  const void* bqkv  = d_in[5];
  const void* Wproj = d_in[6];
  const void* bproj = d_in[7];

  // workspace layout: qkv fp32 (31.5 MB) | attn_out fp32 (10.5 MB) | flag
  float* qkv      = (float*)d_ws;
  float* attn_out = qkv + (size_t)N_TOK * QKV_N;
  int*   flagp    = (int*)(attn_out + (size_t)N_TOK * DIM);

  // 0) detect float dtype of the float-family inputs (fp32 vs bf16)
  detect_kernel<<<1, 256, 0, stream>>>(Wqkv, 4096, flagp);

  // 1) qkv = hs @ Wqkv + bqkv   (2048x1280 @ 1280x3840), fp32 out
  gemm1_kernel<<<dim3(QKV_N / 64, N_TOK / 64), 256, 0, stream>>>(
      hs, Wqkv, bqkv, qkv, N_TOK, QKV_N, DIM, flagp);

  // 2) RoPE on q,k
  rope_kernel<<<(N_TOK * 2 * NHEAD * (HD / 2)) / 256, 256, 0, stream>>>(
      qkv, cosb, sinb, flagp);

  // 3) segment-masked attention (256 threads/block, 64 queries/block)
  int nseg = in_sizes[1] - 1;
  attn_kernel<<<dim3((N_TOK + 63) / 64, nseg, NHEAD), 256, 0, stream>>>(qkv, cu, attn_out);

  // 4) out = attn_out @ Wproj + bproj   (2048x1280 @ 1280x1280)
  gemm2_kernel<<<dim3(DIM / 64, N_TOK / 64), 256, 0, stream>>>(
      attn_out, Wproj, bproj, d_out, N_TOK, DIM, DIM, flagp);
}

// Round 4
// 704.555 us; speedup vs baseline: 6.5949x; 1.9444x over previous
//
#include <hip/hip_runtime.h>
#include <hip/hip_bf16.h>

// Problem constants (Qwen3.5-VL vision attention)
constexpr int N_TOK  = 2048;
constexpr int DIM    = 1280;
constexpr int NHEAD  = 16;
constexpr int HD     = 80;
constexpr int QKV_N  = 3 * DIM;   // 3840

using bf16 = __hip_bfloat16;
typedef __attribute__((ext_vector_type(4))) float f32x4;
typedef __attribute__((ext_vector_type(8))) short short8;  // 8 bf16 = 4 VGPR

__device__ __forceinline__ float b2f(bf16 x) { return __bfloat162float(x); }
__device__ __forceinline__ bf16  f2b(float x) { return __float2bfloat16(x); }

struct __align__(8) bf4 { bf16 x, y, z, w; };

// ---------------------------------------------------------------------------
// Transpose + cast: W fp32 [K][N] -> WT bf16 [N][K]. 32x32 LDS tile.
// ---------------------------------------------------------------------------
__global__ __launch_bounds__(256)
void transpose_cast_kernel(const float* __restrict__ W, bf16* __restrict__ WT,
                           int K, int N) {
  __shared__ float tile[32][33];
  const int n0 = blockIdx.x * 32, k0 = blockIdx.y * 32;
  const int tc = threadIdx.x & 31, tr = threadIdx.x >> 5;  // tr: 0..7
#pragma unroll
  for (int r = tr; r < 32; r += 8)
    tile[r][tc] = W[(size_t)(k0 + r) * N + n0 + tc];
  __syncthreads();
#pragma unroll
  for (int r = tr; r < 32; r += 8)
    WT[(size_t)(n0 + r) * K + k0 + tc] = f2b(tile[tc][r]);
}

// ---------------------------------------------------------------------------
// MFMA GEMM: C[M,N] = A[M,K](fp32, cast->bf16 in staging) @ BT[N,K](bf16) + bias
// BM=BN=128, BK=32. 256 threads = 4 waves in 2x2 grid; wave tile 64x64 =
// 4x4 fragments of 16x16x32 MFMA. LDS tiles padded to stride 40 (2-way max).
// A-frag: lane holds A[row=lane&15][8k of group lane>>4] (8 contiguous bf16).
// B-frag: lane holds B[8k of group lane>>4][col=lane&15] = BT[col][8k..].
// C/D: col=lane&15, row=(lane>>4)*4+reg  [guide m89-verified].
// ---------------------------------------------------------------------------
template <int OBF>  // 1: C bf16, 0: C fp32
__global__ __launch_bounds__(256)
void mfma_gemm(const float* __restrict__ A, const bf16* __restrict__ BT,
               const float* __restrict__ bias, void* __restrict__ C,
               int M, int N, int K) {
  constexpr int LDT = 40;  // padded LDS stride in bf16 elems (80 B)
  __shared__ bf16 As[128 * LDT];
  __shared__ bf16 Bs[128 * LDT];
  const int tid = threadIdx.x;
  const int wid = tid >> 6, lane = tid & 63;
  const int lm = lane & 15, kg = lane >> 4;
  const int wm = (wid >> 1) * 64, wn = (wid & 1) * 64;
  const int m0 = blockIdx.y * 128, n0 = blockIdx.x * 128;

  f32x4 acc[4][4];
#pragma unroll
  for (int i = 0; i < 4; ++i)
#pragma unroll
    for (int j = 0; j < 4; ++j) acc[i][j] = (f32x4){0.f, 0.f, 0.f, 0.f};

  for (int k0 = 0; k0 < K; k0 += 32) {
    // stage A tile: 128 rows x 32 k, fp32 -> bf16 (1024 float4 slots)
#pragma unroll
    for (int i = 0; i < 4; ++i) {
      int s = tid + i * 256;
      int r = s >> 3, f4 = s & 7;
      const float4 v =
          *reinterpret_cast<const float4*>(A + (size_t)(m0 + r) * K + k0 + f4 * 4);
      bf4 t = {f2b(v.x), f2b(v.y), f2b(v.z), f2b(v.w)};
      *reinterpret_cast<bf4*>(&As[r * LDT + f4 * 4]) = t;
    }
    // stage B tile: BT rows n0..n0+127, 32 k each (512 ushort8 slots)
#pragma unroll
    for (int i = 0; i < 2; ++i) {
      int s = tid + i * 256;
      int r = s >> 2, j = s & 3;
      short8 v =
          *reinterpret_cast<const short8*>(BT + (size_t)(n0 + r) * K + k0 + j * 8);
      *reinterpret_cast<short8*>(&Bs[r * LDT + j * 8]) = v;
    }
    __syncthreads();

    short8 af[4], bfr[4];
#pragma unroll
    for (int t = 0; t < 4; ++t) {
      af[t]  = *reinterpret_cast<const short8*>(&As[(wm + t * 16 + lm) * LDT + kg * 8]);
      bfr[t] = *reinterpret_cast<const short8*>(&Bs[(wn + t * 16 + lm) * LDT + kg * 8]);
    }
#pragma unroll
    for (int mi = 0; mi < 4; ++mi)
#pragma unroll
      for (int ni = 0; ni < 4; ++ni)
        acc[mi][ni] = __builtin_amdgcn_mfma_f32_16x16x32_bf16(af[mi], bfr[ni],
                                                              acc[mi][ni], 0, 0, 0);
    __syncthreads();
  }

  // epilogue: bias add + store
#pragma unroll
  for (int mi = 0; mi < 4; ++mi) {
#pragma unroll
    for (int ni = 0; ni < 4; ++ni) {
      const int col = n0 + wn + ni * 16 + lm;
      const float bv = bias[col];
#pragma unroll
      for (int r = 0; r < 4; ++r) {
        const int row = m0 + wm + mi * 16 + kg * 4 + r;
        const float v = acc[mi][ni][r] + bv;
        if constexpr (OBF)
          ((bf16*)C)[(size_t)row * N + col] = f2b(v);
        else
          ((float*)C)[(size_t)row * N + col] = v;
      }
    }
  }
}

// ---------------------------------------------------------------------------
// RoPE on q and k (in-place on bf16 qkv workspace). cos/sin are fp32 inputs.
// ---------------------------------------------------------------------------
__global__ void rope_kernel(bf16* __restrict__ qkv, const float* __restrict__ cosb,
                            const float* __restrict__ sinb) {
  constexpr int HALF = HD / 2;  // 40
  int idx = blockIdx.x * blockDim.x + threadIdx.x;
  int n     = idx / (2 * NHEAD * HALF);
  int rem   = idx % (2 * NHEAD * HALF);
  int which = rem / (NHEAD * HALF);
  int rem2  = rem % (NHEAD * HALF);
  int h     = rem2 / HALF;
  int d     = rem2 % HALF;
  size_t base = (size_t)n * QKV_N + which * DIM + h * HD;
  float x1 = b2f(qkv[base + d]), x2 = b2f(qkv[base + d + HALF]);
  float c1 = cosb[n * HD + d], c2 = cosb[n * HD + d + HALF];
  float s1 = sinb[n * HD + d], s2 = sinb[n * HD + d + HALF];
  qkv[base + d]        = f2b(x1 * c1 - x2 * s1);
  qkv[base + d + HALF] = f2b(x2 * c2 + x1 * s2);
}

// ---------------------------------------------------------------------------
// Flash-style segment-masked attention v3: 8-key batched online softmax.
// Block = 256 threads (4 waves) = 64 queries of one (head, segment, q-tile).
// Lane owns (query, d-quarter). K/V staged bf16->fp32 in LDS.
// Batch of 8: 8 independent dots -> one max/rescale per 8 keys.
// ---------------------------------------------------------------------------
__global__ __launch_bounds__(256)
void attn_kernel(const bf16* __restrict__ qkv, const int* __restrict__ cu,
                 float* __restrict__ out) {
  constexpr int KC = 64;   // keys per LDS chunk
  constexpr int QT = 20;   // head-dim quarter
  __shared__ __align__(16) float Ks[KC * HD];
  __shared__ __align__(16) float Vs[KC * HD];

  const int h = blockIdx.z, seg = blockIdx.y;
  const int s0 = cu[seg], s1 = cu[seg + 1];
  if (s0 + (int)blockIdx.x * 64 >= s1) return;  // uniform early-exit

  const int tid  = threadIdx.x;
  const int wave = tid >> 6, lane = tid & 63;
  const int qloc = lane >> 2, qt = lane & 3;
  const int qi   = s0 + blockIdx.x * 64 + wave * 16 + qloc;
  const bool active = qi < s1;
  const float scale = 0.11180339887498949f;  // 80^-0.5

  float q[QT], acc[QT];
  float m = -1e30f, l = 0.f;
#pragma unroll
  for (int t = 0; t < QT; ++t) { q[t] = 0.f; acc[t] = 0.f; }
  if (active) {
    const bf16* qp = qkv + (size_t)qi * QKV_N + h * HD + qt * QT;
#pragma unroll
    for (int t = 0; t < QT; ++t) q[t] = b2f(qp[t]) * scale;
  }

  for (int k0 = s0; k0 < s1; k0 += KC) {
    const int nk = min(KC, s1 - k0);
    __syncthreads();
    // stage K,V: bf16 -> fp32 LDS (nk rows x 10 ushort8 each)
    for (int i = tid; i < nk * 10; i += 256) {
      int r = i / 10, t8 = i % 10;
      const bf16* kp = qkv + (size_t)(k0 + r) * QKV_N + DIM + h * HD + t8 * 8;
      const bf16* vp = qkv + (size_t)(k0 + r) * QKV_N + 2 * DIM + h * HD + t8 * 8;
      short8 kv = *reinterpret_cast<const short8*>(kp);
      short8 vv = *reinterpret_cast<const short8*>(vp);
#pragma unroll
      for (int e = 0; e < 8; ++e) {
        Ks[r * HD + t8 * 8 + e] = b2f(reinterpret_cast<const bf16*>(&kv)[e]);
        Vs[r * HD + t8 * 8 + e] = b2f(reinterpret_cast<const bf16*>(&vv)[e]);
      }
    }
    __syncthreads();

    for (int j0 = 0; j0 < nk; j0 += 8) {
      float s[8];
#pragma unroll
      for (int jj = 0; jj < 8; ++jj) {
        const float4* kp = reinterpret_cast<const float4*>(Ks + (j0 + jj) * HD + qt * QT);
        float4 a0 = kp[0], a1 = kp[1], a2 = kp[2], a3 = kp[3], a4 = kp[4];
        s[jj] = q[0] * a0.x + q[1] * a0.y + q[2] * a0.z + q[3] * a0.w +
                q[4] * a1.x + q[5] * a1.y + q[6] * a1.z + q[7] * a1.w +
                q[8] * a2.x + q[9] * a2.y + q[10] * a2.z + q[11] * a2.w +
                q[12] * a3.x + q[13] * a3.y + q[14] * a3.z + q[15] * a3.w +
                q[16] * a4.x + q[17] * a4.y + q[18] * a4.z + q[19] * a4.w;
      }
#pragma unroll
      for (int jj = 0; jj < 8; ++jj) {
        s[jj] += __shfl_xor(s[jj], 1);
        s[jj] += __shfl_xor(s[jj], 2);
        if (j0 + jj >= nk) s[jj] = -1e30f;
      }
      float bm = fmaxf(fmaxf(fmaxf(s[0], s[1]), fmaxf(s[2], s[3])),
                       fmaxf(fmaxf(s[4], s[5]), fmaxf(s[6], s[7])));
      float mn = fmaxf(m, bm);
      float f = __expf(m - mn);
      float p[8], sp = 0.f;
#pragma unroll
      for (int jj = 0; jj < 8; ++jj) { p[jj] = __expf(s[jj] - mn); sp += p[jj]; }
      m = mn;
      l = l * f + sp;
#pragma unroll
      for (int t = 0; t < QT; ++t) acc[t] *= f;
#pragma unroll
      for (int jj = 0; jj < 8; ++jj) {
        const float4* vp = reinterpret_cast<const float4*>(Vs + (j0 + jj) * HD + qt * QT);
#pragma unroll
        for (int tv = 0; tv < 5; ++tv) {
          float4 v4 = vp[tv];
          acc[tv * 4 + 0] += p[jj] * v4.x;
          acc[tv * 4 + 1] += p[jj] * v4.y;
          acc[tv * 4 + 2] += p[jj] * v4.z;
          acc[tv * 4 + 3] += p[jj] * v4.w;
        }
      }
    }
  }

  if (active) {
    float inv = 1.f / l;
    float4* op = reinterpret_cast<float4*>(out + (size_t)qi * DIM + h * HD + qt * QT);
#pragma unroll
    for (int tv = 0; tv < 5; ++tv)
      op[tv] = make_float4(acc[tv * 4 + 0] * inv, acc[tv * 4 + 1] * inv,
                           acc[tv * 4 + 2] * inv, acc[tv * 4 + 3] * inv);
  }
}

// ---------------------------------------------------------------------------
extern "C" void kernel_launch(void* const* d_in, const int* in_sizes, int n_in,
                              void* d_out, int out_size, void* d_ws, size_t ws_size,
                              hipStream_t stream) {
  const float* hs    = (const float*)d_in[0];
  const int*   cu    = (const int*)d_in[1];
  const float* cosb  = (const float*)d_in[2];
  const float* sinb  = (const float*)d_in[3];
  const float* Wqkv  = (const float*)d_in[4];
  const float* bqkv  = (const float*)d_in[5];
  const float* Wproj = (const float*)d_in[6];
  const float* bproj = (const float*)d_in[7];

  // ws: qkv bf16 15.73MB | attn_out fp32 10.49MB | WqkvT bf16 9.83MB |
  //     WprojT bf16 3.28MB  = 39.3 MB total (ws proven >= 42 MB in R2)
  bf16*  qkv      = (bf16*)d_ws;
  float* attn_out = (float*)(qkv + (size_t)N_TOK * QKV_N);
  bf16*  WqkvT    = (bf16*)(attn_out + (size_t)N_TOK * DIM);
  bf16*  WprojT   = WqkvT + (size_t)QKV_N * DIM;

  // 0) pre-transpose + cast weights to bf16 K-major
  transpose_cast_kernel<<<dim3(QKV_N / 32, DIM / 32), 256, 0, stream>>>(
      Wqkv, WqkvT, DIM, QKV_N);
  transpose_cast_kernel<<<dim3(DIM / 32, DIM / 32), 256, 0, stream>>>(
      Wproj, WprojT, DIM, DIM);

  // 1) qkv = bf16(hs @ Wqkv + bqkv)   (MFMA)
  mfma_gemm<1><<<dim3(QKV_N / 128, N_TOK / 128), 256, 0, stream>>>(
      hs, WqkvT, bqkv, qkv, N_TOK, QKV_N, DIM);

  // 2) RoPE on q,k (bf16 in-place)
  rope_kernel<<<(N_TOK * 2 * NHEAD * (HD / 2)) / 256, 256, 0, stream>>>(
      qkv, cosb, sinb);

  // 3) segment-masked attention -> attn_out fp32
  int nseg = in_sizes[1] - 1;
  attn_kernel<<<dim3((N_TOK + 63) / 64, nseg, NHEAD), 256, 0, stream>>>(
      qkv, cu, attn_out);

  // 4) out = attn_out @ Wproj + bproj  (MFMA, fp32 out)
  mfma_gemm<0><<<dim3(DIM / 128, N_TOK / 128), 256, 0, stream>>>(
      attn_out, WprojT, bproj, d_out, N_TOK, DIM, DIM);
}

// Round 6
// 177.951 us; speedup vs baseline: 26.1108x; 3.9593x over previous
//
#include <hip/hip_runtime.h>
#include <hip/hip_bf16.h>

// Problem constants (Qwen3.5-VL vision attention)
constexpr int N_TOK  = 2048;
constexpr int DIM    = 1280;
constexpr int NHEAD  = 16;
constexpr int HD     = 80;
constexpr int QKV_N  = 3 * DIM;   // 3840

using bf16 = __hip_bfloat16;
typedef __attribute__((ext_vector_type(4))) float f32x4;
typedef __attribute__((ext_vector_type(8))) short short8;  // 8 bf16 = 4 VGPR

__device__ __forceinline__ float b2f(bf16 x) { return __bfloat162float(x); }
__device__ __forceinline__ bf16  f2b(float x) { return __float2bfloat16(x); }

struct __align__(8) bf4 { bf16 x, y, z, w; };

// ---------------------------------------------------------------------------
// Transpose + cast: W fp32 [K][N] -> WT bf16 [N][K]. 32x32 LDS tile.
// ---------------------------------------------------------------------------
__global__ __launch_bounds__(256)
void transpose_cast_kernel(const float* __restrict__ W, bf16* __restrict__ WT,
                           int K, int N) {
  __shared__ float tile[32][33];
  const int n0 = blockIdx.x * 32, k0 = blockIdx.y * 32;
  const int tc = threadIdx.x & 31, tr = threadIdx.x >> 5;  // tr: 0..7
#pragma unroll
  for (int r = tr; r < 32; r += 8)
    tile[r][tc] = W[(size_t)(k0 + r) * N + n0 + tc];
  __syncthreads();
#pragma unroll
  for (int r = tr; r < 32; r += 8)
    WT[(size_t)(n0 + r) * K + k0 + tc] = f2b(tile[tc][r]);
}

// ---------------------------------------------------------------------------
// MFMA GEMM (R4-verified, unchanged): C = A(fp32->bf16) @ BT(bf16) + bias
// BM=BN=128, BK=32, 4 waves, 4x4 16x16x32 fragments/wave.
// ---------------------------------------------------------------------------
template <int OBF>  // 1: C bf16, 0: C fp32
__global__ __launch_bounds__(256)
void mfma_gemm(const float* __restrict__ A, const bf16* __restrict__ BT,
               const float* __restrict__ bias, void* __restrict__ C,
               int M, int N, int K) {
  constexpr int LDT = 40;
  __shared__ bf16 As[128 * LDT];
  __shared__ bf16 Bs[128 * LDT];
  const int tid = threadIdx.x;
  const int wid = tid >> 6, lane = tid & 63;
  const int lm = lane & 15, kg = lane >> 4;
  const int wm = (wid >> 1) * 64, wn = (wid & 1) * 64;
  const int m0 = blockIdx.y * 128, n0 = blockIdx.x * 128;

  f32x4 acc[4][4];
#pragma unroll
  for (int i = 0; i < 4; ++i)
#pragma unroll
    for (int j = 0; j < 4; ++j) acc[i][j] = (f32x4){0.f, 0.f, 0.f, 0.f};

  for (int k0 = 0; k0 < K; k0 += 32) {
#pragma unroll
    for (int i = 0; i < 4; ++i) {
      int s = tid + i * 256;
      int r = s >> 3, f4 = s & 7;
      const float4 v =
          *reinterpret_cast<const float4*>(A + (size_t)(m0 + r) * K + k0 + f4 * 4);
      bf4 t = {f2b(v.x), f2b(v.y), f2b(v.z), f2b(v.w)};
      *reinterpret_cast<bf4*>(&As[r * LDT + f4 * 4]) = t;
    }
#pragma unroll
    for (int i = 0; i < 2; ++i) {
      int s = tid + i * 256;
      int r = s >> 2, j = s & 3;
      short8 v =
          *reinterpret_cast<const short8*>(BT + (size_t)(n0 + r) * K + k0 + j * 8);
      *reinterpret_cast<short8*>(&Bs[r * LDT + j * 8]) = v;
    }
    __syncthreads();

    short8 af[4], bfr[4];
#pragma unroll
    for (int t = 0; t < 4; ++t) {
      af[t]  = *reinterpret_cast<const short8*>(&As[(wm + t * 16 + lm) * LDT + kg * 8]);
      bfr[t] = *reinterpret_cast<const short8*>(&Bs[(wn + t * 16 + lm) * LDT + kg * 8]);
    }
#pragma unroll
    for (int mi = 0; mi < 4; ++mi)
#pragma unroll
      for (int ni = 0; ni < 4; ++ni)
        acc[mi][ni] = __builtin_amdgcn_mfma_f32_16x16x32_bf16(af[mi], bfr[ni],
                                                              acc[mi][ni], 0, 0, 0);
    __syncthreads();
  }

#pragma unroll
  for (int mi = 0; mi < 4; ++mi) {
#pragma unroll
    for (int ni = 0; ni < 4; ++ni) {
      const int col = n0 + wn + ni * 16 + lm;
      const float bv = bias[col];
#pragma unroll
      for (int r = 0; r < 4; ++r) {
        const int row = m0 + wm + mi * 16 + kg * 4 + r;
        const float v = acc[mi][ni][r] + bv;
        if constexpr (OBF)
          ((bf16*)C)[(size_t)row * N + col] = f2b(v);
        else
          ((float*)C)[(size_t)row * N + col] = v;
      }
    }
  }
}

// ---------------------------------------------------------------------------
// RoPE on q and k (in-place on bf16 qkv workspace). cos/sin fp32.
// ---------------------------------------------------------------------------
__global__ void rope_kernel(bf16* __restrict__ qkv, const float* __restrict__ cosb,
                            const float* __restrict__ sinb) {
  constexpr int HALF = HD / 2;  // 40
  int idx = blockIdx.x * blockDim.x + threadIdx.x;
  int n     = idx / (2 * NHEAD * HALF);
  int rem   = idx % (2 * NHEAD * HALF);
  int which = rem / (NHEAD * HALF);
  int rem2  = rem % (NHEAD * HALF);
  int h     = rem2 / HALF;
  int d     = rem2 % HALF;
  size_t base = (size_t)n * QKV_N + which * DIM + h * HD;
  float x1 = b2f(qkv[base + d]), x2 = b2f(qkv[base + d + HALF]);
  float c1 = cosb[n * HD + d], c2 = cosb[n * HD + d + HALF];
  float s1 = sinb[n * HD + d], s2 = sinb[n * HD + d + HALF];
  qkv[base + d]        = f2b(x1 * c1 - x2 * s1);
  qkv[base + d + HALF] = f2b(x2 * c2 + x1 * s2);
}

// ---------------------------------------------------------------------------
// MFMA flash attention. Block = 256 thr (4 waves) = 64 queries of (h, seg).
// Wave owns 16 q. Chunk = 64 keys.
//  S^T = K.Q^T  (A = K LDS [key][d], B = Q regs)  -> D col=q, row=key
//  softmax per q: in-lane 16-val tree + shfl_xor(16,32); scalar m,l,f
//  P -> bf16 -> per-wave LDS [q][key] (b64 writes, same-wave DS ordering)
//  O^T += V^T.P^T (A = V^T LDS [d][key] XOR-swizzled, B = P LDS) -> col=q,row=d
//
// R6 fix: KSTR 88 -> 104 so the d=64..95 chunk reads stay IN-ROW, and the pad
// columns 80..103 are zero-filled once at start. R5 read unwritten LDS /
// crossed rows there; 0 x (NaN|Inf) garbage = NaN. All LDS reads now touch
// initialized memory only.
// ---------------------------------------------------------------------------
constexpr int KC   = 64;   // keys per chunk
constexpr int KSTR = 104;  // Ks stride: 52-dword rows, 20r%32 bank spread, >=96
constexpr int VSTR = 72;   // Vt stride: 144B, 16B-aligned; + key XOR-swizzle
constexpr int PSTR = 72;   // Pl stride

__global__ __launch_bounds__(256)
void attn_mfma_kernel(const bf16* __restrict__ qkv, const int* __restrict__ cu,
                      float* __restrict__ out) {
  __shared__ bf16 Ks[KC * KSTR];        // 13312 B  [key][d], cols 80..103 = 0
  __shared__ bf16 Vt[HD * VSTR];        // 11520 B  [d][key^swz]
  __shared__ bf16 Pl[4 * 16 * PSTR];    //  9216 B  per-wave [q][key]

  const int h = blockIdx.z, seg = blockIdx.y;
  const int s0 = cu[seg], s1 = cu[seg + 1];
  if (s0 + (int)blockIdx.x * 64 >= s1) return;  // uniform early-exit

  const int tid  = threadIdx.x;
  const int wave = tid >> 6, lane = tid & 63;
  const int lm = lane & 15, kg = lane >> 4;
  const int qrow = s0 + blockIdx.x * 64 + wave * 16 + lm;  // this lane's query
  const float scale = 0.11180339887498949f;  // 80^-0.5

  // zero-fill Ks pad columns 80..103 (3 short8 slots per row, 192 total)
  if (tid < 192) {
    int r = tid / 3, sl = tid % 3;
    *reinterpret_cast<short8*>(&Ks[r * KSTR + 80 + sl * 8]) =
        (short8){0, 0, 0, 0, 0, 0, 0, 0};
  }

  // Q B-fragments: lane holds Q[q=lm][d = ck*32 + kg*8 .. +7], zero-padded
  short8 qa[3];
#pragma unroll
  for (int ck = 0; ck < 3; ++ck) {
    const int dbase = ck * 32 + kg * 8;
    if (qrow < s1 && dbase < HD)
      qa[ck] = *reinterpret_cast<const short8*>(
          qkv + (size_t)qrow * QKV_N + h * HD + dbase);
    else
      qa[ck] = (short8){0, 0, 0, 0, 0, 0, 0, 0};
  }

  f32x4 oacc[5];
#pragma unroll
  for (int dt = 0; dt < 5; ++dt) oacc[dt] = (f32x4){0.f, 0.f, 0.f, 0.f};
  float m = -1e30f, l = 0.f;

  const int pbase = wave * 16 * PSTR + lm * PSTR;  // this lane's P row

  for (int k0 = s0; k0 < s1; k0 += KC) {
    const int nk = min(KC, s1 - k0);
    __syncthreads();
    // ---- stage K [key][d] (b128 writes, cols 0..79) ----
    for (int i = tid; i < nk * 10; i += 256) {
      int r = i / 10, sl = i % 10;
      *reinterpret_cast<short8*>(&Ks[r * KSTR + sl * 8]) =
          *reinterpret_cast<const short8*>(
              qkv + (size_t)(k0 + r) * QKV_N + DIM + h * HD + sl * 8);
    }
    // ---- stage V^T [d][key ^ ((d>>3&7)<<3)] (scalar writes, bank-spread) ----
    for (int i = tid; i < nk * 10; i += 256) {
      int r = i / 10, sl = i % 10;
      short8 vv = *reinterpret_cast<const short8*>(
          qkv + (size_t)(k0 + r) * QKV_N + 2 * DIM + h * HD + sl * 8);
      const int swz = (sl & 7) << 3;  // d>>3 == sl for e<8
#pragma unroll
      for (int e = 0; e < 8; ++e)
        Vt[(sl * 8 + e) * VSTR + (r ^ swz)] =
            reinterpret_cast<const bf16*>(&vv)[e];
    }
    if (nk < KC) {  // zero-fill tails (never taken for this problem's cu)
      for (int i = nk * 10 + tid; i < KC * 10; i += 256) {
        int r = i / 10, sl = i % 10;
        *reinterpret_cast<short8*>(&Ks[r * KSTR + sl * 8]) =
            (short8){0, 0, 0, 0, 0, 0, 0, 0};
      }
      for (int i = tid; i < HD * KC; i += 256) {
        int d = i / KC, key = i % KC;
        if (key >= nk) Vt[d * VSTR + (key ^ (((d >> 3) & 7) << 3))] = f2b(0.f);
      }
    }
    __syncthreads();

    // ---- S^T = K . Q^T : 4 key-tiles x 3 d-chunks (d 80..95 reads = pad 0) ----
    f32x4 sc[4];
#pragma unroll
    for (int mi = 0; mi < 4; ++mi) {
      sc[mi] = (f32x4){0.f, 0.f, 0.f, 0.f};
#pragma unroll
      for (int ck = 0; ck < 3; ++ck) {
        short8 ka = *reinterpret_cast<const short8*>(
            &Ks[(mi * 16 + lm) * KSTR + ck * 32 + kg * 8]);
        sc[mi] = __builtin_amdgcn_mfma_f32_16x16x32_bf16(ka, qa[ck], sc[mi], 0, 0, 0);
      }
    }
    // scale + tail-mask
#pragma unroll
    for (int mi = 0; mi < 4; ++mi) sc[mi] *= scale;
    if (nk < KC) {
#pragma unroll
      for (int mi = 0; mi < 4; ++mi)
#pragma unroll
        for (int r = 0; r < 4; ++r)
          if (mi * 16 + kg * 4 + r >= nk) sc[mi][r] = -1e30f;
    }
    // ---- online softmax (per q = lm; lane holds 16 key-scores) ----
    f32x4 m4 = sc[0];
#pragma unroll
    for (int mi = 1; mi < 4; ++mi) {
      m4[0] = fmaxf(m4[0], sc[mi][0]); m4[1] = fmaxf(m4[1], sc[mi][1]);
      m4[2] = fmaxf(m4[2], sc[mi][2]); m4[3] = fmaxf(m4[3], sc[mi][3]);
    }
    float rm = fmaxf(fmaxf(m4[0], m4[1]), fmaxf(m4[2], m4[3]));
    rm = fmaxf(rm, __shfl_xor(rm, 16));
    rm = fmaxf(rm, __shfl_xor(rm, 32));
    const float mnew = fmaxf(m, rm);
    const float fs = __expf(m - mnew);
    m = mnew;
    float rs = 0.f;
    f32x4 pp[4];
#pragma unroll
    for (int mi = 0; mi < 4; ++mi) {
#pragma unroll
      for (int r = 0; r < 4; ++r) {
        pp[mi][r] = __expf(sc[mi][r] - mnew);
        rs += pp[mi][r];
      }
    }
    rs += __shfl_xor(rs, 16);
    rs += __shfl_xor(rs, 32);
    l = l * fs + rs;
#pragma unroll
    for (int dt = 0; dt < 5; ++dt) oacc[dt] *= fs;
    // ---- pack P -> bf16, write per-wave LDS [q][key] (4x b64) ----
#pragma unroll
    for (int mi = 0; mi < 4; ++mi) {
      __align__(8) bf16 w[4] = {f2b(pp[mi][0]), f2b(pp[mi][1]),
                                f2b(pp[mi][2]), f2b(pp[mi][3])};
      *reinterpret_cast<uint2*>(&Pl[pbase + mi * 16 + kg * 4]) =
          *reinterpret_cast<const uint2*>(w);
    }
    // ---- O^T += V^T . P^T : 2 key-chunks x 5 d-tiles ----
#pragma unroll
    for (int kc = 0; kc < 2; ++kc) {
      short8 pb = *reinterpret_cast<const short8*>(&Pl[pbase + kc * 32 + kg * 8]);
#pragma unroll
      for (int dt = 0; dt < 5; ++dt) {
        const int d = dt * 16 + lm;
        short8 va = *reinterpret_cast<const short8*>(
            &Vt[d * VSTR + ((kc * 32 + kg * 8) ^ (((d >> 3) & 7) << 3))]);
        oacc[dt] = __builtin_amdgcn_mfma_f32_16x16x32_bf16(va, pb, oacc[dt], 0, 0, 0);
      }
    }
  }

  // ---- epilogue: O^T frag col=q=lm, row=d=dt*16+kg*4+r ----
  if (qrow < s1) {
    const float inv = 1.f / l;
    float* op = out + (size_t)qrow * DIM + h * HD;
#pragma unroll
    for (int dt = 0; dt < 5; ++dt)
#pragma unroll
      for (int r = 0; r < 4; ++r)
        op[dt * 16 + kg * 4 + r] = oacc[dt][r] * inv;
  }
}

// ---------------------------------------------------------------------------
extern "C" void kernel_launch(void* const* d_in, const int* in_sizes, int n_in,
                              void* d_out, int out_size, void* d_ws, size_t ws_size,
                              hipStream_t stream) {
  const float* hs    = (const float*)d_in[0];
  const int*   cu    = (const int*)d_in[1];
  const float* cosb  = (const float*)d_in[2];
  const float* sinb  = (const float*)d_in[3];
  const float* Wqkv  = (const float*)d_in[4];
  const float* bqkv  = (const float*)d_in[5];
  const float* Wproj = (const float*)d_in[6];
  const float* bproj = (const float*)d_in[7];

  // ws: qkv bf16 15.73MB | attn_out fp32 10.49MB | WqkvT 9.83MB | WprojT 3.28MB
  bf16*  qkv      = (bf16*)d_ws;
  float* attn_out = (float*)(qkv + (size_t)N_TOK * QKV_N);
  bf16*  WqkvT    = (bf16*)(attn_out + (size_t)N_TOK * DIM);
  bf16*  WprojT   = WqkvT + (size_t)QKV_N * DIM;

  // 0) pre-transpose + cast weights to bf16 K-major
  transpose_cast_kernel<<<dim3(QKV_N / 32, DIM / 32), 256, 0, stream>>>(
      Wqkv, WqkvT, DIM, QKV_N);
  transpose_cast_kernel<<<dim3(DIM / 32, DIM / 32), 256, 0, stream>>>(
      Wproj, WprojT, DIM, DIM);

  // 1) qkv = bf16(hs @ Wqkv + bqkv)
  mfma_gemm<1><<<dim3(QKV_N / 128, N_TOK / 128), 256, 0, stream>>>(
      hs, WqkvT, bqkv, qkv, N_TOK, QKV_N, DIM);

  // 2) RoPE on q,k
  rope_kernel<<<(N_TOK * 2 * NHEAD * (HD / 2)) / 256, 256, 0, stream>>>(
      qkv, cosb, sinb);

  // 3) MFMA flash attention -> attn_out fp32
  int nseg = in_sizes[1] - 1;
  attn_mfma_kernel<<<dim3(N_TOK / 64, nseg, NHEAD), 256, 0, stream>>>(
      qkv, cu, attn_out);

  // 4) out = attn_out @ Wproj + bproj (fp32 out)
  mfma_gemm<0><<<dim3(DIM / 128, N_TOK / 128), 256, 0, stream>>>(
      attn_out, WprojT, bproj, d_out, N_TOK, DIM, DIM);
}

// Round 7
// 155.906 us; speedup vs baseline: 29.8029x; 1.1414x over previous
//
#include <hip/hip_runtime.h>
#include <hip/hip_bf16.h>

// Problem constants (Qwen3.5-VL vision attention)
constexpr int N_TOK  = 2048;
constexpr int DIM    = 1280;
constexpr int NHEAD  = 16;
constexpr int HD     = 80;
constexpr int QKV_N  = 3 * DIM;   // 3840

using bf16 = __hip_bfloat16;
typedef __attribute__((ext_vector_type(4))) float f32x4;
typedef __attribute__((ext_vector_type(8))) short short8;  // 8 bf16 = 4 VGPR

__device__ __forceinline__ float b2f(bf16 x) { return __bfloat162float(x); }
__device__ __forceinline__ bf16  f2b(float x) { return __float2bfloat16(x); }

// async global->LDS, 16B per lane; dest is wave-uniform base + lane*16
typedef const __attribute__((address_space(1))) unsigned int* gas_u32;
typedef __attribute__((address_space(3))) unsigned int* las_u32;
__device__ __forceinline__ void gload_lds16(const void* g, void* l) {
  __builtin_amdgcn_global_load_lds((gas_u32)g, (las_u32)l, 16, 0, 0);
}

// ---------------------------------------------------------------------------
// fp32 -> bf16 row-major cast (hs), 8 elems/thread, short8 stores.
// ---------------------------------------------------------------------------
__global__ __launch_bounds__(256)
void cast_bf16_kernel(const float* __restrict__ in, bf16* __restrict__ out) {
  const int i = (blockIdx.x * 256 + threadIdx.x) * 8;
  const float4 a = *reinterpret_cast<const float4*>(in + i);
  const float4 b = *reinterpret_cast<const float4*>(in + i + 4);
  __align__(16) bf16 w[8] = {f2b(a.x), f2b(a.y), f2b(a.z), f2b(a.w),
                             f2b(b.x), f2b(b.y), f2b(b.z), f2b(b.w)};
  *reinterpret_cast<short8*>(out + i) = *reinterpret_cast<const short8*>(w);
}

// ---------------------------------------------------------------------------
// Transpose + cast: W fp32 [K][N] -> WT bf16 [N][K]. 32x32 LDS tile.
// ---------------------------------------------------------------------------
__global__ __launch_bounds__(256)
void transpose_cast_kernel(const float* __restrict__ W, bf16* __restrict__ WT,
                           int K, int N) {
  __shared__ float tile[32][33];
  const int n0 = blockIdx.x * 32, k0 = blockIdx.y * 32;
  const int tc = threadIdx.x & 31, tr = threadIdx.x >> 5;  // tr: 0..7
#pragma unroll
  for (int r = tr; r < 32; r += 8)
    tile[r][tc] = W[(size_t)(k0 + r) * N + n0 + tc];
  __syncthreads();
#pragma unroll
  for (int r = tr; r < 32; r += 8)
    WT[(size_t)(n0 + r) * K + k0 + tc] = f2b(tile[tc][r]);
}

// ---------------------------------------------------------------------------
// m97-style MFMA GEMM: C = A(bf16,[M][K]) @ BT(bf16,[N][K]) + bias(fp32)
// BM=BN=128, BK=64, 256 thr = 4 waves (2x2), 4x4 16x16x32 frags/wave.
// Staging: global_load_lds width-16, LINEAR LDS dest; XOR swizzle applied by
// pre-swizzling the per-lane GLOBAL source block (b ^ (row&7)); ds_read_b128
// applies the same XOR -> 2-way max bank aliasing (free per m136).
// ---------------------------------------------------------------------------
template <int OBF>  // 1: C bf16, 0: C fp32
__global__ __launch_bounds__(256)
void mfma_gemm(const bf16* __restrict__ A, const bf16* __restrict__ BT,
               const float* __restrict__ bias, void* __restrict__ C,
               int M, int N, int K) {
  __shared__ bf16 As[128 * 64];  // 16 KB, linear [row][64]
  __shared__ bf16 Bs[128 * 64];
  const int tid = threadIdx.x;
  const int wid = tid >> 6, lane = tid & 63;
  const int lm = lane & 15, kg = lane >> 4;
  const int wm = (wid >> 1) * 64, wn = (wid & 1) * 64;
  const int m0 = blockIdx.y * 128, n0 = blockIdx.x * 128;

  // staging geometry: slot = i*4 + wid (16 slots x 8 rows); lane covers
  // row slot*8 + (lane>>3), 16B block (lane&7), source block ^ (row&7)
  const int srow = lane >> 3;               // row within slot = row&7
  const int sblk = (lane & 7) ^ srow;       // pre-swizzled source block

  f32x4 acc[4][4];
#pragma unroll
  for (int i = 0; i < 4; ++i)
#pragma unroll
    for (int j = 0; j < 4; ++j) acc[i][j] = (f32x4){0.f, 0.f, 0.f, 0.f};

  for (int k0 = 0; k0 < K; k0 += 64) {
#pragma unroll
    for (int i = 0; i < 4; ++i) {
      const int slot = i * 4 + wid;
      const int row = slot * 8 + srow;
      gload_lds16(A + (size_t)(m0 + row) * K + k0 + sblk * 8, &As[slot * 512]);
      gload_lds16(BT + (size_t)(n0 + row) * K + k0 + sblk * 8, &Bs[slot * 512]);
    }
    __syncthreads();  // drains vmcnt (compiler-inserted) + barrier

#pragma unroll
    for (int kh = 0; kh < 2; ++kh) {
      short8 af[4], bfr[4];
#pragma unroll
      for (int t = 0; t < 4; ++t) {
        const int ar = wm + t * 16 + lm;
        af[t] = *reinterpret_cast<const short8*>(
            &As[ar * 64 + ((kh * 4 + kg) ^ (ar & 7)) * 8]);
        const int br = wn + t * 16 + lm;
        bfr[t] = *reinterpret_cast<const short8*>(
            &Bs[br * 64 + ((kh * 4 + kg) ^ (br & 7)) * 8]);
      }
#pragma unroll
      for (int mi = 0; mi < 4; ++mi)
#pragma unroll
        for (int ni = 0; ni < 4; ++ni)
          acc[mi][ni] = __builtin_amdgcn_mfma_f32_16x16x32_bf16(
              af[mi], bfr[ni], acc[mi][ni], 0, 0, 0);
    }
    __syncthreads();
  }

  // epilogue: bias add + store (C/D: col=lane&15, row=(lane>>4)*4+reg)
#pragma unroll
  for (int mi = 0; mi < 4; ++mi) {
#pragma unroll
    for (int ni = 0; ni < 4; ++ni) {
      const int col = n0 + wn + ni * 16 + lm;
      const float bv = bias[col];
#pragma unroll
      for (int r = 0; r < 4; ++r) {
        const int row = m0 + wm + mi * 16 + kg * 4 + r;
        const float v = acc[mi][ni][r] + bv;
        if constexpr (OBF)
          ((bf16*)C)[(size_t)row * N + col] = f2b(v);
        else
          ((float*)C)[(size_t)row * N + col] = v;
      }
    }
  }
}

// ---------------------------------------------------------------------------
// RoPE on q and k (in-place on bf16 qkv workspace). cos/sin fp32.
// ---------------------------------------------------------------------------
__global__ void rope_kernel(bf16* __restrict__ qkv, const float* __restrict__ cosb,
                            const float* __restrict__ sinb) {
  constexpr int HALF = HD / 2;  // 40
  int idx = blockIdx.x * blockDim.x + threadIdx.x;
  int n     = idx / (2 * NHEAD * HALF);
  int rem   = idx % (2 * NHEAD * HALF);
  int which = rem / (NHEAD * HALF);
  int rem2  = rem % (NHEAD * HALF);
  int h     = rem2 / HALF;
  int d     = rem2 % HALF;
  size_t base = (size_t)n * QKV_N + which * DIM + h * HD;
  float x1 = b2f(qkv[base + d]), x2 = b2f(qkv[base + d + HALF]);
  float c1 = cosb[n * HD + d], c2 = cosb[n * HD + d + HALF];
  float s1 = sinb[n * HD + d], s2 = sinb[n * HD + d + HALF];
  qkv[base + d]        = f2b(x1 * c1 - x2 * s1);
  qkv[base + d + HALF] = f2b(x2 * c2 + x1 * s2);
}

// ---------------------------------------------------------------------------
// MFMA flash attention (R6-verified math) + R7 changes:
//  - T14 async-stage split: next chunk's K/V global->reg loads issued BEFORE
//    computing current chunk; reg->LDS commit after the barrier.
//  - V^T transpose staging packs 4 keys per b64 ds_write (4x fewer DS ops).
//  - epilogue writes bf16 (feeds gemm2's bf16 A path).
// Global key rows clamped to s1-1: masked scores give p=0 for tails.
// ---------------------------------------------------------------------------
constexpr int KC   = 64;   // keys per chunk
constexpr int KSTR = 104;  // Ks stride: >=96 so all d-chunk reads stay in-row
constexpr int VSTR = 72;   // Vt stride + key XOR swizzle
constexpr int PSTR = 72;   // Pl stride

__global__ __launch_bounds__(256)
void attn_mfma_kernel(const bf16* __restrict__ qkv, const int* __restrict__ cu,
                      bf16* __restrict__ out) {
  __shared__ bf16 Ks[KC * KSTR];        // 13312 B [key][d], cols 80..103 = 0
  __shared__ bf16 Vt[HD * VSTR];        // 11520 B [d][key^swz]
  __shared__ bf16 Pl[4 * 16 * PSTR];    //  9216 B per-wave [q][key]

  const int h = blockIdx.z, seg = blockIdx.y;
  const int s0 = cu[seg], s1 = cu[seg + 1];
  if (s0 + (int)blockIdx.x * 64 >= s1) return;  // uniform early-exit

  const int tid  = threadIdx.x;
  const int wave = tid >> 6, lane = tid & 63;
  const int lm = lane & 15, kg = lane >> 4;
  const int qrow = s0 + blockIdx.x * 64 + wave * 16 + lm;
  const float scale = 0.11180339887498949f;  // 80^-0.5

  // zero-fill Ks pad columns 80..103 once (never overwritten)
  if (tid < 192) {
    int r = tid / 3, sl = tid % 3;
    *reinterpret_cast<short8*>(&Ks[r * KSTR + 80 + sl * 8]) =
        (short8){0, 0, 0, 0, 0, 0, 0, 0};
  }

  // Q B-fragments: lane holds Q[q=lm][d = ck*32 + kg*8 .. +7], zero-padded
  short8 qa[3];
#pragma unroll
  for (int ck = 0; ck < 3; ++ck) {
    const int dbase = ck * 32 + kg * 8;
    if (qrow < s1 && dbase < HD)
      qa[ck] = *reinterpret_cast<const short8*>(
          qkv + (size_t)qrow * QKV_N + h * HD + dbase);
    else
      qa[ck] = (short8){0, 0, 0, 0, 0, 0, 0, 0};
  }

  // prefetch registers: K 3 slots/thread (640 slots), V 4 keys x 1 slot
  short8 kreg[3], vreg[4];
  const int vgrp = tid / 10, vsl = tid % 10;  // valid for tid<160
  auto issue = [&](int k0) {
#pragma unroll
    for (int t = 0; t < 3; ++t) {
      const int s = tid + t * 256;
      if (s < 640) {
        const int r = min(k0 + s / 10, s1 - 1);
        kreg[t] = *reinterpret_cast<const short8*>(
            qkv + (size_t)r * QKV_N + DIM + h * HD + (s % 10) * 8);
      }
    }
    if (tid < 160) {
#pragma unroll
      for (int e = 0; e < 4; ++e) {
        const int r = min(k0 + vgrp * 4 + e, s1 - 1);
        vreg[e] = *reinterpret_cast<const short8*>(
            qkv + (size_t)r * QKV_N + 2 * DIM + h * HD + vsl * 8);
      }
    }
  };
  auto commit = [&]() {
#pragma unroll
    for (int t = 0; t < 3; ++t) {
      const int s = tid + t * 256;
      if (s < 640)
        *reinterpret_cast<short8*>(&Ks[(s / 10) * KSTR + (s % 10) * 8]) = kreg[t];
    }
    if (tid < 160) {
      const int r0 = vgrp * 4;
      const int swz = (vsl & 7) << 3;
#pragma unroll
      for (int de = 0; de < 8; ++de) {
        __align__(8) bf16 w[4] = {reinterpret_cast<const bf16*>(&vreg[0])[de],
                                  reinterpret_cast<const bf16*>(&vreg[1])[de],
                                  reinterpret_cast<const bf16*>(&vreg[2])[de],
                                  reinterpret_cast<const bf16*>(&vreg[3])[de]};
        *reinterpret_cast<uint2*>(&Vt[(vsl * 8 + de) * VSTR + (r0 ^ swz)]) =
            *reinterpret_cast<const uint2*>(w);
      }
    }
  };

  f32x4 oacc[5];
#pragma unroll
  for (int dt = 0; dt < 5; ++dt) oacc[dt] = (f32x4){0.f, 0.f, 0.f, 0.f};
  float m = -1e30f, l = 0.f;
  const int pbase = wave * 16 * PSTR + lm * PSTR;

  issue(s0);
  commit();
  __syncthreads();

  for (int k0 = s0; k0 < s1; k0 += KC) {
    const int nk = min(KC, s1 - k0);
    const bool more = (k0 + KC) < s1;
    if (more) issue(k0 + KC);  // global loads in flight during compute below

    // ---- S^T = K . Q^T : 4 key-tiles x 3 d-chunks ----
    f32x4 sc[4];
#pragma unroll
    for (int mi = 0; mi < 4; ++mi) {
      sc[mi] = (f32x4){0.f, 0.f, 0.f, 0.f};
#pragma unroll
      for (int ck = 0; ck < 3; ++ck) {
        short8 ka = *reinterpret_cast<const short8*>(
            &Ks[(mi * 16 + lm) * KSTR + ck * 32 + kg * 8]);
        sc[mi] = __builtin_amdgcn_mfma_f32_16x16x32_bf16(ka, qa[ck], sc[mi], 0, 0, 0);
      }
    }
#pragma unroll
    for (int mi = 0; mi < 4; ++mi) sc[mi] *= scale;
    if (nk < KC) {
#pragma unroll
      for (int mi = 0; mi < 4; ++mi)
#pragma unroll
        for (int r = 0; r < 4; ++r)
          if (mi * 16 + kg * 4 + r >= nk) sc[mi][r] = -1e30f;
    }
    // ---- online softmax (per q = lm; lane holds 16 key-scores) ----
    f32x4 m4 = sc[0];
#pragma unroll
    for (int mi = 1; mi < 4; ++mi) {
      m4[0] = fmaxf(m4[0], sc[mi][0]); m4[1] = fmaxf(m4[1], sc[mi][1]);
      m4[2] = fmaxf(m4[2], sc[mi][2]); m4[3] = fmaxf(m4[3], sc[mi][3]);
    }
    float rm = fmaxf(fmaxf(m4[0], m4[1]), fmaxf(m4[2], m4[3]));
    rm = fmaxf(rm, __shfl_xor(rm, 16));
    rm = fmaxf(rm, __shfl_xor(rm, 32));
    const float mnew = fmaxf(m, rm);
    const float fs = __expf(m - mnew);
    m = mnew;
    float rs = 0.f;
    f32x4 pp[4];
#pragma unroll
    for (int mi = 0; mi < 4; ++mi) {
#pragma unroll
      for (int r = 0; r < 4; ++r) {
        pp[mi][r] = __expf(sc[mi][r] - mnew);
        rs += pp[mi][r];
      }
    }
    rs += __shfl_xor(rs, 16);
    rs += __shfl_xor(rs, 32);
    l = l * fs + rs;
#pragma unroll
    for (int dt = 0; dt < 5; ++dt) oacc[dt] *= fs;
    // ---- pack P -> bf16 -> per-wave LDS [q][key] ----
#pragma unroll
    for (int mi = 0; mi < 4; ++mi) {
      __align__(8) bf16 w[4] = {f2b(pp[mi][0]), f2b(pp[mi][1]),
                                f2b(pp[mi][2]), f2b(pp[mi][3])};
      *reinterpret_cast<uint2*>(&Pl[pbase + mi * 16 + kg * 4]) =
          *reinterpret_cast<const uint2*>(w);
    }
    // ---- O^T += V^T . P^T : 2 key-chunks x 5 d-tiles ----
#pragma unroll
    for (int kc = 0; kc < 2; ++kc) {
      short8 pb = *reinterpret_cast<const short8*>(&Pl[pbase + kc * 32 + kg * 8]);
#pragma unroll
      for (int dt = 0; dt < 5; ++dt) {
        const int d = dt * 16 + lm;
        short8 va = *reinterpret_cast<const short8*>(
            &Vt[d * VSTR + ((kc * 32 + kg * 8) ^ (((d >> 3) & 7) << 3))]);
        oacc[dt] = __builtin_amdgcn_mfma_f32_16x16x32_bf16(va, pb, oacc[dt], 0, 0, 0);
      }
    }

    __syncthreads();           // all waves done reading K/V LDS
    if (more) commit();        // next chunk regs -> LDS
    __syncthreads();
  }

  // ---- epilogue: O^T frag col=q=lm, row=d=dt*16+kg*4+r; bf16 out ----
  if (qrow < s1) {
    const float inv = 1.f / l;
    bf16* op = out + (size_t)qrow * DIM + h * HD;
#pragma unroll
    for (int dt = 0; dt < 5; ++dt) {
      __align__(8) bf16 w[4] = {f2b(oacc[dt][0] * inv), f2b(oacc[dt][1] * inv),
                                f2b(oacc[dt][2] * inv), f2b(oacc[dt][3] * inv)};
      *reinterpret_cast<uint2*>(op + dt * 16 + kg * 4) =
          *reinterpret_cast<const uint2*>(w);
    }
  }
}

// ---------------------------------------------------------------------------
extern "C" void kernel_launch(void* const* d_in, const int* in_sizes, int n_in,
                              void* d_out, int out_size, void* d_ws, size_t ws_size,
                              hipStream_t stream) {
  const float* hs    = (const float*)d_in[0];
  const int*   cu    = (const int*)d_in[1];
  const float* cosb  = (const float*)d_in[2];
  const float* sinb  = (const float*)d_in[3];
  const float* Wqkv  = (const float*)d_in[4];
  const float* bqkv  = (const float*)d_in[5];
  const float* Wproj = (const float*)d_in[6];
  const float* bproj = (const float*)d_in[7];

  // ws: qkv bf16 15.73MB | attn_out bf16 5.24MB | WqkvT 9.83MB | WprojT 3.28MB
  //     | hs_bf16 5.24MB  = 39.3 MB
  bf16* qkv      = (bf16*)d_ws;
  bf16* attn_out = qkv + (size_t)N_TOK * QKV_N;
  bf16* WqkvT    = attn_out + (size_t)N_TOK * DIM;
  bf16* WprojT   = WqkvT + (size_t)QKV_N * DIM;
  bf16* hsb      = WprojT + (size_t)DIM * DIM;

  // 0) casts/transposes (run once per launch; ~15 us total)
  cast_bf16_kernel<<<(N_TOK * DIM) / (256 * 8), 256, 0, stream>>>(hs, hsb);
  transpose_cast_kernel<<<dim3(QKV_N / 32, DIM / 32), 256, 0, stream>>>(
      Wqkv, WqkvT, DIM, QKV_N);
  transpose_cast_kernel<<<dim3(DIM / 32, DIM / 32), 256, 0, stream>>>(
      Wproj, WprojT, DIM, DIM);

  // 1) qkv = bf16(hsb @ Wqkv + bqkv)
  mfma_gemm<1><<<dim3(QKV_N / 128, N_TOK / 128), 256, 0, stream>>>(
      hsb, WqkvT, bqkv, qkv, N_TOK, QKV_N, DIM);

  // 2) RoPE on q,k
  rope_kernel<<<(N_TOK * 2 * NHEAD * (HD / 2)) / 256, 256, 0, stream>>>(
      qkv, cosb, sinb);

  // 3) MFMA flash attention -> attn_out (bf16)
  int nseg = in_sizes[1] - 1;
  attn_mfma_kernel<<<dim3(N_TOK / 64, nseg, NHEAD), 256, 0, stream>>>(
      qkv, cu, attn_out);

  // 4) out = attn_out @ Wproj + bproj (fp32 out)
  mfma_gemm<0><<<dim3(DIM / 128, N_TOK / 128), 256, 0, stream>>>(
      attn_out, WprojT, bproj, d_out, N_TOK, DIM, DIM);
}

// Round 8
// 142.020 us; speedup vs baseline: 32.7169x; 1.0978x over previous
//
#include <hip/hip_runtime.h>
#include <hip/hip_bf16.h>

// Problem constants (Qwen3.5-VL vision attention)
constexpr int N_TOK  = 2048;
constexpr int DIM    = 1280;
constexpr int NHEAD  = 16;
constexpr int HD     = 80;
constexpr int QKV_N  = 3 * DIM;   // 3840

using bf16 = __hip_bfloat16;
typedef __attribute__((ext_vector_type(4))) float f32x4;
typedef __attribute__((ext_vector_type(8))) short short8;  // 8 bf16 = 4 VGPR

__device__ __forceinline__ float b2f(bf16 x) { return __bfloat162float(x); }
__device__ __forceinline__ bf16  f2b(float x) { return __float2bfloat16(x); }

// async global->LDS, 16B per lane; dest is wave-uniform base + lane*16
typedef const __attribute__((address_space(1))) unsigned int* gas_u32;
typedef __attribute__((address_space(3))) unsigned int* las_u32;
__device__ __forceinline__ void gload_lds16(const void* g, void* l) {
  __builtin_amdgcn_global_load_lds((gas_u32)g, (las_u32)l, 16, 0, 0);
}

// ---------------------------------------------------------------------------
// Fused prep: z=0 cast hs->bf16, z=1 transpose Wqkv, z=2 transpose Wproj.
// ---------------------------------------------------------------------------
__device__ __forceinline__ void transpose_body(const float* __restrict__ W,
                                               bf16* __restrict__ WT, int K, int N) {
  __shared__ float tile[32][33];
  const int n0 = blockIdx.x * 32, k0 = blockIdx.y * 32;
  const int tc = threadIdx.x & 31, tr = threadIdx.x >> 5;
#pragma unroll
  for (int r = tr; r < 32; r += 8)
    tile[r][tc] = W[(size_t)(k0 + r) * N + n0 + tc];
  __syncthreads();
#pragma unroll
  for (int r = tr; r < 32; r += 8)
    WT[(size_t)(n0 + r) * K + k0 + tc] = f2b(tile[tc][r]);
}

__global__ __launch_bounds__(256)
void prep_kernel(const float* __restrict__ hs, bf16* __restrict__ hsb,
                 const float* __restrict__ Wqkv, bf16* __restrict__ WqkvT,
                 const float* __restrict__ Wproj, bf16* __restrict__ WprojT) {
  if (blockIdx.z == 0) {
    const int bid = blockIdx.y * gridDim.x + blockIdx.x;
    if (bid >= (N_TOK * DIM) / 2048) return;
    const int i = bid * 2048 + threadIdx.x * 8;
    const float4 a = *reinterpret_cast<const float4*>(hs + i);
    const float4 b = *reinterpret_cast<const float4*>(hs + i + 4);
    __align__(16) bf16 w[8] = {f2b(a.x), f2b(a.y), f2b(a.z), f2b(a.w),
                               f2b(b.x), f2b(b.y), f2b(b.z), f2b(b.w)};
    *reinterpret_cast<short8*>(hsb + i) = *reinterpret_cast<const short8*>(w);
  } else if (blockIdx.z == 1) {
    transpose_body(Wqkv, WqkvT, DIM, QKV_N);           // grid (120,40)
  } else {
    if (blockIdx.x >= DIM / 32) return;
    transpose_body(Wproj, WprojT, DIM, DIM);           // (40,40)
  }
}

// ---------------------------------------------------------------------------
// m97-style MFMA GEMM (R7-verified): C = A(bf16) @ BT(bf16) + bias(fp32)
// BM=BN=128, BK=64, 4 waves, global_load_lds w16 + pre-swizzled source.
// ---------------------------------------------------------------------------
template <int OBF>  // 1: C bf16, 0: C fp32
__global__ __launch_bounds__(256)
void mfma_gemm(const bf16* __restrict__ A, const bf16* __restrict__ BT,
               const float* __restrict__ bias, void* __restrict__ C,
               int M, int N, int K) {
  __shared__ bf16 As[128 * 64];
  __shared__ bf16 Bs[128 * 64];
  const int tid = threadIdx.x;
  const int wid = tid >> 6, lane = tid & 63;
  const int lm = lane & 15, kg = lane >> 4;
  const int wm = (wid >> 1) * 64, wn = (wid & 1) * 64;
  const int m0 = blockIdx.y * 128, n0 = blockIdx.x * 128;

  const int srow = lane >> 3;
  const int sblk = (lane & 7) ^ srow;

  f32x4 acc[4][4];
#pragma unroll
  for (int i = 0; i < 4; ++i)
#pragma unroll
    for (int j = 0; j < 4; ++j) acc[i][j] = (f32x4){0.f, 0.f, 0.f, 0.f};

  for (int k0 = 0; k0 < K; k0 += 64) {
#pragma unroll
    for (int i = 0; i < 4; ++i) {
      const int slot = i * 4 + wid;
      const int row = slot * 8 + srow;
      gload_lds16(A + (size_t)(m0 + row) * K + k0 + sblk * 8, &As[slot * 512]);
      gload_lds16(BT + (size_t)(n0 + row) * K + k0 + sblk * 8, &Bs[slot * 512]);
    }
    __syncthreads();

#pragma unroll
    for (int kh = 0; kh < 2; ++kh) {
      short8 af[4], bfr[4];
#pragma unroll
      for (int t = 0; t < 4; ++t) {
        const int ar = wm + t * 16 + lm;
        af[t] = *reinterpret_cast<const short8*>(
            &As[ar * 64 + ((kh * 4 + kg) ^ (ar & 7)) * 8]);
        const int br = wn + t * 16 + lm;
        bfr[t] = *reinterpret_cast<const short8*>(
            &Bs[br * 64 + ((kh * 4 + kg) ^ (br & 7)) * 8]);
      }
#pragma unroll
      for (int mi = 0; mi < 4; ++mi)
#pragma unroll
        for (int ni = 0; ni < 4; ++ni)
          acc[mi][ni] = __builtin_amdgcn_mfma_f32_16x16x32_bf16(
              af[mi], bfr[ni], acc[mi][ni], 0, 0, 0);
    }
    __syncthreads();
  }

#pragma unroll
  for (int mi = 0; mi < 4; ++mi) {
#pragma unroll
    for (int ni = 0; ni < 4; ++ni) {
      const int col = n0 + wn + ni * 16 + lm;
      const float bv = bias[col];
#pragma unroll
      for (int r = 0; r < 4; ++r) {
        const int row = m0 + wm + mi * 16 + kg * 4 + r;
        const float v = acc[mi][ni][r] + bv;
        if constexpr (OBF)
          ((bf16*)C)[(size_t)row * N + col] = f2b(v);
        else
          ((float*)C)[(size_t)row * N + col] = v;
      }
    }
  }
}

// ---------------------------------------------------------------------------
// RoPE on q and k (in-place on bf16 qkv workspace). cos/sin fp32.
// ---------------------------------------------------------------------------
__global__ void rope_kernel(bf16* __restrict__ qkv, const float* __restrict__ cosb,
                            const float* __restrict__ sinb) {
  constexpr int HALF = HD / 2;  // 40
  int idx = blockIdx.x * blockDim.x + threadIdx.x;
  int n     = idx / (2 * NHEAD * HALF);
  int rem   = idx % (2 * NHEAD * HALF);
  int which = rem / (NHEAD * HALF);
  int rem2  = rem % (NHEAD * HALF);
  int h     = rem2 / HALF;
  int d     = rem2 % HALF;
  size_t base = (size_t)n * QKV_N + which * DIM + h * HD;
  float x1 = b2f(qkv[base + d]), x2 = b2f(qkv[base + d + HALF]);
  float c1 = cosb[n * HD + d], c2 = cosb[n * HD + d + HALF];
  float s1 = sinb[n * HD + d], s2 = sinb[n * HD + d + HALF];
  qkv[base + d]        = f2b(x1 * c1 - x2 * s1);
  qkv[base + d + HALF] = f2b(x2 * c2 + x1 * s2);
}

// ---------------------------------------------------------------------------
// MFMA flash attention, R8: double-buffered K/V LDS -> ONE barrier per chunk;
// T13 defer-max (skip rescale while max grows <= 8); T5 setprio around MFMA.
// Schedule per chunk c: compute buf[c&1] | commit(c+1)->buf[c&1^1] (regs
// issued at c-1; readers of that buf finished before last barrier) |
// issue(c+2) | barrier.
// ---------------------------------------------------------------------------
constexpr int KC   = 64;   // keys per chunk
constexpr int KSTR = 104;  // Ks stride: >=96 so all d-chunk reads stay in-row
constexpr int VSTR = 72;   // Vt stride + key XOR swizzle
constexpr int PSTR = 72;   // Pl stride

__global__ __launch_bounds__(256)
void attn_mfma_kernel(const bf16* __restrict__ qkv, const int* __restrict__ cu,
                      bf16* __restrict__ out) {
  __shared__ bf16 Ks[2][KC * KSTR];      // 2 x 13312 B, cols 80..103 = 0
  __shared__ bf16 Vt[2][HD * VSTR];      // 2 x 11520 B
  __shared__ bf16 Pl[4 * 16 * PSTR];     //     9216 B per-wave [q][key]

  const int h = blockIdx.z, seg = blockIdx.y;
  const int s0 = cu[seg], s1 = cu[seg + 1];
  if (s0 + (int)blockIdx.x * 64 >= s1) return;  // uniform early-exit

  const int tid  = threadIdx.x;
  const int wave = tid >> 6, lane = tid & 63;
  const int lm = lane & 15, kg = lane >> 4;
  const int qrow = s0 + blockIdx.x * 64 + wave * 16 + lm;
  const float scale = 0.11180339887498949f;  // 80^-0.5

  // zero-fill Ks pad columns 80..103 in BOTH buffers (never overwritten)
  if (tid < 192) {
    int r = tid / 3, sl = tid % 3;
#pragma unroll
    for (int b = 0; b < 2; ++b)
      *reinterpret_cast<short8*>(&Ks[b][r * KSTR + 80 + sl * 8]) =
          (short8){0, 0, 0, 0, 0, 0, 0, 0};
  }

  // Q B-fragments: lane holds Q[q=lm][d = ck*32 + kg*8 .. +7], zero-padded
  short8 qa[3];
#pragma unroll
  for (int ck = 0; ck < 3; ++ck) {
    const int dbase = ck * 32 + kg * 8;
    if (qrow < s1 && dbase < HD)
      qa[ck] = *reinterpret_cast<const short8*>(
          qkv + (size_t)qrow * QKV_N + h * HD + dbase);
    else
      qa[ck] = (short8){0, 0, 0, 0, 0, 0, 0, 0};
  }

  // prefetch registers: K 3 slots/thread (640 slots), V 4 keys x 1 slot
  short8 kreg[3], vreg[4];
  const int vgrp = tid / 10, vsl = tid % 10;  // valid for tid<160
  auto issue = [&](int c) {
    const int k0 = s0 + c * KC;
#pragma unroll
    for (int t = 0; t < 3; ++t) {
      const int s = tid + t * 256;
      if (s < 640) {
        const int r = min(k0 + s / 10, s1 - 1);
        kreg[t] = *reinterpret_cast<const short8*>(
            qkv + (size_t)r * QKV_N + DIM + h * HD + (s % 10) * 8);
      }
    }
    if (tid < 160) {
#pragma unroll
      for (int e = 0; e < 4; ++e) {
        const int r = min(k0 + vgrp * 4 + e, s1 - 1);
        vreg[e] = *reinterpret_cast<const short8*>(
            qkv + (size_t)r * QKV_N + 2 * DIM + h * HD + vsl * 8);
      }
    }
  };
  auto commit = [&](int buf) {
#pragma unroll
    for (int t = 0; t < 3; ++t) {
      const int s = tid + t * 256;
      if (s < 640)
        *reinterpret_cast<short8*>(&Ks[buf][(s / 10) * KSTR + (s % 10) * 8]) =
            kreg[t];
    }
    if (tid < 160) {
      const int r0 = vgrp * 4;
      const int swz = (vsl & 7) << 3;
#pragma unroll
      for (int de = 0; de < 8; ++de) {
        __align__(8) bf16 w[4] = {reinterpret_cast<const bf16*>(&vreg[0])[de],
                                  reinterpret_cast<const bf16*>(&vreg[1])[de],
                                  reinterpret_cast<const bf16*>(&vreg[2])[de],
                                  reinterpret_cast<const bf16*>(&vreg[3])[de]};
        *reinterpret_cast<uint2*>(&Vt[buf][(vsl * 8 + de) * VSTR + (r0 ^ swz)]) =
            *reinterpret_cast<const uint2*>(w);
      }
    }
  };

  f32x4 oacc[5];
#pragma unroll
  for (int dt = 0; dt < 5; ++dt) oacc[dt] = (f32x4){0.f, 0.f, 0.f, 0.f};
  float m = -1e30f, l = 0.f;
  const int pbase = wave * 16 * PSTR + lm * PSTR;
  const int nch = (s1 - s0 + KC - 1) / KC;

  issue(0);
  commit(0);
  if (nch > 1) issue(1);
  __syncthreads();

  for (int c = 0; c < nch; ++c) {
    const int cur = c & 1;
    const int nk = min(KC, s1 - (s0 + c * KC));

    // ---- S^T = K . Q^T : 4 key-tiles x 3 d-chunks ----
    f32x4 sc[4];
    __builtin_amdgcn_s_setprio(1);
#pragma unroll
    for (int mi = 0; mi < 4; ++mi) {
      sc[mi] = (f32x4){0.f, 0.f, 0.f, 0.f};
#pragma unroll
      for (int ck = 0; ck < 3; ++ck) {
        short8 ka = *reinterpret_cast<const short8*>(
            &Ks[cur][(mi * 16 + lm) * KSTR + ck * 32 + kg * 8]);
        sc[mi] = __builtin_amdgcn_mfma_f32_16x16x32_bf16(ka, qa[ck], sc[mi], 0, 0, 0);
      }
    }
    __builtin_amdgcn_s_setprio(0);
#pragma unroll
    for (int mi = 0; mi < 4; ++mi) sc[mi] *= scale;
    if (nk < KC) {
#pragma unroll
      for (int mi = 0; mi < 4; ++mi)
#pragma unroll
        for (int r = 0; r < 4; ++r)
          if (mi * 16 + kg * 4 + r >= nk) sc[mi][r] = -1e30f;
    }
    // ---- online softmax with defer-max (T13) ----
    f32x4 m4 = sc[0];
#pragma unroll
    for (int mi = 1; mi < 4; ++mi) {
      m4[0] = fmaxf(m4[0], sc[mi][0]); m4[1] = fmaxf(m4[1], sc[mi][1]);
      m4[2] = fmaxf(m4[2], sc[mi][2]); m4[3] = fmaxf(m4[3], sc[mi][3]);
    }
    float rm = fmaxf(fmaxf(m4[0], m4[1]), fmaxf(m4[2], m4[3]));
    rm = fmaxf(rm, __shfl_xor(rm, 16));
    rm = fmaxf(rm, __shfl_xor(rm, 32));
    const float mnew = fmaxf(m, rm);
    if (!__all(mnew - m <= 8.0f)) {  // rescale only on real max growth
      const float fs = __expf(m - mnew);
      m = mnew;
      l *= fs;
#pragma unroll
      for (int dt = 0; dt < 5; ++dt) oacc[dt] *= fs;
    }
    float rs = 0.f;
    f32x4 pp[4];
#pragma unroll
    for (int mi = 0; mi < 4; ++mi) {
#pragma unroll
      for (int r = 0; r < 4; ++r) {
        pp[mi][r] = __expf(sc[mi][r] - m);  // bounded by e^8
        rs += pp[mi][r];
      }
    }
    rs += __shfl_xor(rs, 16);
    rs += __shfl_xor(rs, 32);
    l += rs;
    // ---- pack P -> bf16 -> per-wave LDS [q][key] (same-wave DS order) ----
#pragma unroll
    for (int mi = 0; mi < 4; ++mi) {
      __align__(8) bf16 w[4] = {f2b(pp[mi][0]), f2b(pp[mi][1]),
                                f2b(pp[mi][2]), f2b(pp[mi][3])};
      *reinterpret_cast<uint2*>(&Pl[pbase + mi * 16 + kg * 4]) =
          *reinterpret_cast<const uint2*>(w);
    }
    // ---- O^T += V^T . P^T : 2 key-chunks x 5 d-tiles ----
    __builtin_amdgcn_s_setprio(1);
#pragma unroll
    for (int kc = 0; kc < 2; ++kc) {
      short8 pb = *reinterpret_cast<const short8*>(&Pl[pbase + kc * 32 + kg * 8]);
#pragma unroll
      for (int dt = 0; dt < 5; ++dt) {
        const int d = dt * 16 + lm;
        short8 va = *reinterpret_cast<const short8*>(
            &Vt[cur][d * VSTR + ((kc * 32 + kg * 8) ^ (((d >> 3) & 7) << 3))]);
        oacc[dt] = __builtin_amdgcn_mfma_f32_16x16x32_bf16(va, pb, oacc[dt], 0, 0, 0);
      }
    }
    __builtin_amdgcn_s_setprio(0);

    // pipeline: fill the other buffer (its readers finished pre-barrier)
    if (c + 1 < nch) commit(cur ^ 1);
    if (c + 2 < nch) issue(c + 2);
    __syncthreads();
  }

  // ---- epilogue: O^T frag col=q=lm, row=d=dt*16+kg*4+r; bf16 out ----
  if (qrow < s1) {
    const float inv = 1.f / l;
    bf16* op = out + (size_t)qrow * DIM + h * HD;
#pragma unroll
    for (int dt = 0; dt < 5; ++dt) {
      __align__(8) bf16 w[4] = {f2b(oacc[dt][0] * inv), f2b(oacc[dt][1] * inv),
                                f2b(oacc[dt][2] * inv), f2b(oacc[dt][3] * inv)};
      *reinterpret_cast<uint2*>(op + dt * 16 + kg * 4) =
          *reinterpret_cast<const uint2*>(w);
    }
  }
}

// ---------------------------------------------------------------------------
extern "C" void kernel_launch(void* const* d_in, const int* in_sizes, int n_in,
                              void* d_out, int out_size, void* d_ws, size_t ws_size,
                              hipStream_t stream) {
  const float* hs    = (const float*)d_in[0];
  const int*   cu    = (const int*)d_in[1];
  const float* cosb  = (const float*)d_in[2];
  const float* sinb  = (const float*)d_in[3];
  const float* Wqkv  = (const float*)d_in[4];
  const float* bqkv  = (const float*)d_in[5];
  const float* Wproj = (const float*)d_in[6];
  const float* bproj = (const float*)d_in[7];

  // ws: qkv bf16 15.73MB | attn_out bf16 5.24MB | WqkvT 9.83MB | WprojT 3.28MB
  //     | hs_bf16 5.24MB  = 39.3 MB
  bf16* qkv      = (bf16*)d_ws;
  bf16* attn_out = qkv + (size_t)N_TOK * QKV_N;
  bf16* WqkvT    = attn_out + (size_t)N_TOK * DIM;
  bf16* WprojT   = WqkvT + (size_t)QKV_N * DIM;
  bf16* hsb      = WprojT + (size_t)DIM * DIM;

  // 0) fused prep: cast hs + transpose both weights
  prep_kernel<<<dim3(QKV_N / 32, DIM / 32, 3), 256, 0, stream>>>(
      hs, hsb, Wqkv, WqkvT, Wproj, WprojT);

  // 1) qkv = bf16(hsb @ Wqkv + bqkv)
  mfma_gemm<1><<<dim3(QKV_N / 128, N_TOK / 128), 256, 0, stream>>>(
      hsb, WqkvT, bqkv, qkv, N_TOK, QKV_N, DIM);

  // 2) RoPE on q,k
  rope_kernel<<<(N_TOK * 2 * NHEAD * (HD / 2)) / 256, 256, 0, stream>>>(
      qkv, cosb, sinb);

  // 3) MFMA flash attention -> attn_out (bf16)
  int nseg = in_sizes[1] - 1;
  attn_mfma_kernel<<<dim3(N_TOK / 64, nseg, NHEAD), 256, 0, stream>>>(
      qkv, cu, attn_out);

  // 4) out = attn_out @ Wproj + bproj (fp32 out)
  mfma_gemm<0><<<dim3(DIM / 128, N_TOK / 128), 256, 0, stream>>>(
      attn_out, WprojT, bproj, d_out, N_TOK, DIM, DIM);
}

// Round 9
// 127.883 us; speedup vs baseline: 36.3337x; 1.1105x over previous
//
#include <hip/hip_runtime.h>
#include <hip/hip_bf16.h>

// Problem constants (Qwen3.5-VL vision attention)
constexpr int N_TOK  = 2048;
constexpr int DIM    = 1280;
constexpr int NHEAD  = 16;
constexpr int HD     = 80;
constexpr int QKV_N  = 3 * DIM;   // 3840

using bf16 = __hip_bfloat16;
typedef __attribute__((ext_vector_type(4))) float f32x4;
typedef __attribute__((ext_vector_type(8))) short short8;  // 8 bf16 = 4 VGPR

__device__ __forceinline__ float b2f(bf16 x) { return __bfloat162float(x); }
__device__ __forceinline__ bf16  f2b(float x) { return __float2bfloat16(x); }

// async global->LDS, 16B per lane; dest is wave-uniform base + lane*16
typedef const __attribute__((address_space(1))) unsigned int* gas_u32;
typedef __attribute__((address_space(3))) unsigned int* las_u32;
__device__ __forceinline__ void gload_lds16(const void* g, void* l) {
  __builtin_amdgcn_global_load_lds((gas_u32)g, (las_u32)l, 16, 0, 0);
}

// ---------------------------------------------------------------------------
// Fused prep: z=0 cast hs->bf16, z=1 transpose Wqkv, z=2 transpose Wproj.
// ---------------------------------------------------------------------------
__device__ __forceinline__ void transpose_body(const float* __restrict__ W,
                                               bf16* __restrict__ WT, int K, int N) {
  __shared__ float tile[32][33];
  const int n0 = blockIdx.x * 32, k0 = blockIdx.y * 32;
  const int tc = threadIdx.x & 31, tr = threadIdx.x >> 5;
#pragma unroll
  for (int r = tr; r < 32; r += 8)
    tile[r][tc] = W[(size_t)(k0 + r) * N + n0 + tc];
  __syncthreads();
#pragma unroll
  for (int r = tr; r < 32; r += 8)
    WT[(size_t)(n0 + r) * K + k0 + tc] = f2b(tile[tc][r]);
}

__global__ __launch_bounds__(256)
void prep_kernel(const float* __restrict__ hs, bf16* __restrict__ hsb,
                 const float* __restrict__ Wqkv, bf16* __restrict__ WqkvT,
                 const float* __restrict__ Wproj, bf16* __restrict__ WprojT) {
  if (blockIdx.z == 0) {
    const int bid = blockIdx.y * gridDim.x + blockIdx.x;
    if (bid >= (N_TOK * DIM) / 2048) return;
    const int i = bid * 2048 + threadIdx.x * 8;
    const float4 a = *reinterpret_cast<const float4*>(hs + i);
    const float4 b = *reinterpret_cast<const float4*>(hs + i + 4);
    __align__(16) bf16 w[8] = {f2b(a.x), f2b(a.y), f2b(a.z), f2b(a.w),
                               f2b(b.x), f2b(b.y), f2b(b.z), f2b(b.w)};
    *reinterpret_cast<short8*>(hsb + i) = *reinterpret_cast<const short8*>(w);
  } else if (blockIdx.z == 1) {
    transpose_body(Wqkv, WqkvT, DIM, QKV_N);           // grid (120,40)
  } else {
    if (blockIdx.x >= DIM / 32) return;
    transpose_body(Wproj, WprojT, DIM, DIM);           // (40,40)
  }
}

// ---------------------------------------------------------------------------
// m97-style MFMA GEMM (R7-verified): C = A(bf16) @ BT(bf16) + bias(fp32)
// BM=BN=128, BK=64, 4 waves, global_load_lds w16 + pre-swizzled source.
// ---------------------------------------------------------------------------
template <int OBF>  // 1: C bf16, 0: C fp32
__global__ __launch_bounds__(256)
void mfma_gemm(const bf16* __restrict__ A, const bf16* __restrict__ BT,
               const float* __restrict__ bias, void* __restrict__ C,
               int M, int N, int K) {
  __shared__ bf16 As[128 * 64];
  __shared__ bf16 Bs[128 * 64];
  const int tid = threadIdx.x;
  const int wid = tid >> 6, lane = tid & 63;
  const int lm = lane & 15, kg = lane >> 4;
  const int wm = (wid >> 1) * 64, wn = (wid & 1) * 64;
  const int m0 = blockIdx.y * 128, n0 = blockIdx.x * 128;

  const int srow = lane >> 3;
  const int sblk = (lane & 7) ^ srow;

  f32x4 acc[4][4];
#pragma unroll
  for (int i = 0; i < 4; ++i)
#pragma unroll
    for (int j = 0; j < 4; ++j) acc[i][j] = (f32x4){0.f, 0.f, 0.f, 0.f};

  for (int k0 = 0; k0 < K; k0 += 64) {
#pragma unroll
    for (int i = 0; i < 4; ++i) {
      const int slot = i * 4 + wid;
      const int row = slot * 8 + srow;
      gload_lds16(A + (size_t)(m0 + row) * K + k0 + sblk * 8, &As[slot * 512]);
      gload_lds16(BT + (size_t)(n0 + row) * K + k0 + sblk * 8, &Bs[slot * 512]);
    }
    __syncthreads();

#pragma unroll
    for (int kh = 0; kh < 2; ++kh) {
      short8 af[4], bfr[4];
#pragma unroll
      for (int t = 0; t < 4; ++t) {
        const int ar = wm + t * 16 + lm;
        af[t] = *reinterpret_cast<const short8*>(
            &As[ar * 64 + ((kh * 4 + kg) ^ (ar & 7)) * 8]);
        const int br = wn + t * 16 + lm;
        bfr[t] = *reinterpret_cast<const short8*>(
            &Bs[br * 64 + ((kh * 4 + kg) ^ (br & 7)) * 8]);
      }
#pragma unroll
      for (int mi = 0; mi < 4; ++mi)
#pragma unroll
        for (int ni = 0; ni < 4; ++ni)
          acc[mi][ni] = __builtin_amdgcn_mfma_f32_16x16x32_bf16(
              af[mi], bfr[ni], acc[mi][ni], 0, 0, 0);
    }
    __syncthreads();
  }

#pragma unroll
  for (int mi = 0; mi < 4; ++mi) {
#pragma unroll
    for (int ni = 0; ni < 4; ++ni) {
      const int col = n0 + wn + ni * 16 + lm;
      const float bv = bias[col];
#pragma unroll
      for (int r = 0; r < 4; ++r) {
        const int row = m0 + wm + mi * 16 + kg * 4 + r;
        const float v = acc[mi][ni][r] + bv;
        if constexpr (OBF)
          ((bf16*)C)[(size_t)row * N + col] = f2b(v);
        else
          ((float*)C)[(size_t)row * N + col] = v;
      }
    }
  }
}

// ---------------------------------------------------------------------------
// RoPE on q and k (in-place on bf16 qkv workspace). cos/sin fp32.
// ---------------------------------------------------------------------------
__global__ void rope_kernel(bf16* __restrict__ qkv, const float* __restrict__ cosb,
                            const float* __restrict__ sinb) {
  constexpr int HALF = HD / 2;  // 40
  int idx = blockIdx.x * blockDim.x + threadIdx.x;
  int n     = idx / (2 * NHEAD * HALF);
  int rem   = idx % (2 * NHEAD * HALF);
  int which = rem / (NHEAD * HALF);
  int rem2  = rem % (NHEAD * HALF);
  int h     = rem2 / HALF;
  int d     = rem2 % HALF;
  size_t base = (size_t)n * QKV_N + which * DIM + h * HD;
  float x1 = b2f(qkv[base + d]), x2 = b2f(qkv[base + d + HALF]);
  float c1 = cosb[n * HD + d], c2 = cosb[n * HD + d + HALF];
  float s1 = sinb[n * HD + d], s2 = sinb[n * HD + d + HALF];
  qkv[base + d]        = f2b(x1 * c1 - x2 * s1);
  qkv[base + d + HALF] = f2b(x2 * c2 + x1 * s2);
}

// ---------------------------------------------------------------------------
// MFMA flash attention, R9: 8 waves / QBLK=128 (16 waves/CU, 4/SIMD).
// dbuf K + SINGLE-buffer Vt (commitV at chunk start overlaps QK+softmax;
// midbar before PV). VSTR 72->88 fixes ~9-way Vt write-bank conflict.
// Per chunk: commitV(c) | QK(c) Ks[cur] | commitK(c+1)->Ks[cur^1] |
// issue(v c+1, k c+2) | softmax+pack | MIDBAR | PV(c) | ENDBAR.
// ---------------------------------------------------------------------------
constexpr int KC   = 64;   // keys per chunk
constexpr int KSTR = 104;  // >=96 (in-row d-chunks), 208B rows: 2-way banks
constexpr int VSTR = 88;   // 176B rows: 16B-aligned reads, ~4-way writes
constexpr int PSTR = 72;   // 144B rows

__global__ __launch_bounds__(512)
void attn_mfma_kernel(const bf16* __restrict__ qkv, const int* __restrict__ cu,
                      bf16* __restrict__ out) {
  __shared__ bf16 Ks[2][KC * KSTR];      // 26624 B, cols 80..103 zeroed
  __shared__ bf16 Vt[HD * VSTR];         // 14080 B [d][key^swz]
  __shared__ bf16 Pl[8 * 16 * PSTR];     // 18432 B per-wave [q][key]

  const int h = blockIdx.z, seg = blockIdx.y;
  const int s0 = cu[seg], s1 = cu[seg + 1];
  if (s0 + (int)blockIdx.x * 128 >= s1) return;  // uniform early-exit

  const int tid  = threadIdx.x;
  const int wid  = tid >> 6, lane = tid & 63;
  const int lm = lane & 15, kg = lane >> 4;
  const int qrow = s0 + blockIdx.x * 128 + wid * 16 + lm;
  const float scale = 0.11180339887498949f;  // 80^-0.5

  // zero-fill Ks pad columns 80..103 in BOTH buffers (2*64 rows * 3 slots)
  if (tid < 384) {
    int b = tid / 192, rem = tid % 192, r = rem / 3, sl = rem % 3;
    *reinterpret_cast<short8*>(&Ks[b][r * KSTR + 80 + sl * 8]) =
        (short8){0, 0, 0, 0, 0, 0, 0, 0};
  }

  // Q B-fragments: lane holds Q[q=lm][d = ck*32 + kg*8 .. +7], zero-padded
  short8 qa[3];
#pragma unroll
  for (int ck = 0; ck < 3; ++ck) {
    const int dbase = ck * 32 + kg * 8;
    if (qrow < s1 && dbase < HD)
      qa[ck] = *reinterpret_cast<const short8*>(
          qkv + (size_t)qrow * QKV_N + h * HD + dbase);
    else
      qa[ck] = (short8){0, 0, 0, 0, 0, 0, 0, 0};
  }

  // prefetch regs: K 640 slots over 512 thr (2 rounds), V 160 thr x 4 keys
  short8 kreg[2], vreg[4];
  const int vgrp = tid / 10, vsl = tid % 10;  // valid for tid<160
  auto issueK = [&](int c) {
    const int k0 = s0 + c * KC;
    {
      const int r = min(k0 + tid / 10, s1 - 1);
      kreg[0] = *reinterpret_cast<const short8*>(
          qkv + (size_t)r * QKV_N + DIM + h * HD + (tid % 10) * 8);
    }
    if (tid < 128) {
      const int s = tid + 512;
      const int r = min(k0 + s / 10, s1 - 1);
      kreg[1] = *reinterpret_cast<const short8*>(
          qkv + (size_t)r * QKV_N + DIM + h * HD + (s % 10) * 8);
    }
  };
  auto commitK = [&](int buf) {
    *reinterpret_cast<short8*>(&Ks[buf][(tid / 10) * KSTR + (tid % 10) * 8]) =
        kreg[0];
    if (tid < 128) {
      const int s = tid + 512;
      *reinterpret_cast<short8*>(&Ks[buf][(s / 10) * KSTR + (s % 10) * 8]) =
          kreg[1];
    }
  };
  auto issueV = [&](int c) {
    if (tid < 160) {
      const int k0 = s0 + c * KC;
#pragma unroll
      for (int e = 0; e < 4; ++e) {
        const int r = min(k0 + vgrp * 4 + e, s1 - 1);
        vreg[e] = *reinterpret_cast<const short8*>(
            qkv + (size_t)r * QKV_N + 2 * DIM + h * HD + vsl * 8);
      }
    }
  };
  auto commitV = [&]() {
    if (tid < 160) {
      const int r0 = vgrp * 4;
      const int swz = (vsl & 7) << 3;
#pragma unroll
      for (int de = 0; de < 8; ++de) {
        __align__(8) bf16 w[4] = {reinterpret_cast<const bf16*>(&vreg[0])[de],
                                  reinterpret_cast<const bf16*>(&vreg[1])[de],
                                  reinterpret_cast<const bf16*>(&vreg[2])[de],
                                  reinterpret_cast<const bf16*>(&vreg[3])[de]};
        *reinterpret_cast<uint2*>(&Vt[(vsl * 8 + de) * VSTR + (r0 ^ swz)]) =
            *reinterpret_cast<const uint2*>(w);
      }
    }
  };

  f32x4 oacc[5];
#pragma unroll
  for (int dt = 0; dt < 5; ++dt) oacc[dt] = (f32x4){0.f, 0.f, 0.f, 0.f};
  float m = -1e30f, l = 0.f;
  const int pbase = (wid * 16 + lm) * PSTR;
  const int nch = (s1 - s0 + KC - 1) / KC;

  issueK(0);
  issueV(0);
  commitK(0);
  if (nch > 1) issueK(1);
  __syncthreads();

  for (int c = 0; c < nch; ++c) {
    const int cur = c & 1;
    const int nk = min(KC, s1 - (s0 + c * KC));

    // 1. commit V(c) into the single Vt buffer (readers drained at endbar)
    commitV();

    // 2. S^T = K . Q^T : 4 key-tiles x 3 d-chunks
    f32x4 sc[4];
    __builtin_amdgcn_s_setprio(1);
#pragma unroll
    for (int mi = 0; mi < 4; ++mi) {
      sc[mi] = (f32x4){0.f, 0.f, 0.f, 0.f};
#pragma unroll
      for (int ck = 0; ck < 3; ++ck) {
        short8 ka = *reinterpret_cast<const short8*>(
            &Ks[cur][(mi * 16 + lm) * KSTR + ck * 32 + kg * 8]);
        sc[mi] = __builtin_amdgcn_mfma_f32_16x16x32_bf16(ka, qa[ck], sc[mi], 0, 0, 0);
      }
    }
    __builtin_amdgcn_s_setprio(0);

    // 3+4. pipeline: commit K(c+1), issue V(c+1), issue K(c+2)
    if (c + 1 < nch) {
      commitK(cur ^ 1);
      issueV(c + 1);
    }
    if (c + 2 < nch) issueK(c + 2);

    // 5. scale, tail-mask, online softmax (defer-max), pack P
#pragma unroll
    for (int mi = 0; mi < 4; ++mi) sc[mi] *= scale;
    if (nk < KC) {
#pragma unroll
      for (int mi = 0; mi < 4; ++mi)
#pragma unroll
        for (int r = 0; r < 4; ++r)
          if (mi * 16 + kg * 4 + r >= nk) sc[mi][r] = -1e30f;
    }
    f32x4 m4 = sc[0];
#pragma unroll
    for (int mi = 1; mi < 4; ++mi) {
      m4[0] = fmaxf(m4[0], sc[mi][0]); m4[1] = fmaxf(m4[1], sc[mi][1]);
      m4[2] = fmaxf(m4[2], sc[mi][2]); m4[3] = fmaxf(m4[3], sc[mi][3]);
    }
    float rm = fmaxf(fmaxf(m4[0], m4[1]), fmaxf(m4[2], m4[3]));
    rm = fmaxf(rm, __shfl_xor(rm, 16));
    rm = fmaxf(rm, __shfl_xor(rm, 32));
    const float mnew = fmaxf(m, rm);
    if (!__all(mnew - m <= 8.0f)) {  // rescale only on real max growth
      const float fs = __expf(m - mnew);
      m = mnew;
      l *= fs;
#pragma unroll
      for (int dt = 0; dt < 5; ++dt) oacc[dt] *= fs;
    }
    float rs = 0.f;
    f32x4 pp[4];
#pragma unroll
    for (int mi = 0; mi < 4; ++mi) {
#pragma unroll
      for (int r = 0; r < 4; ++r) {
        pp[mi][r] = __expf(sc[mi][r] - m);  // bounded by e^8
        rs += pp[mi][r];
      }
    }
    rs += __shfl_xor(rs, 16);
    rs += __shfl_xor(rs, 32);
    l += rs;
#pragma unroll
    for (int mi = 0; mi < 4; ++mi) {
      __align__(8) bf16 w[4] = {f2b(pp[mi][0]), f2b(pp[mi][1]),
                                f2b(pp[mi][2]), f2b(pp[mi][3])};
      *reinterpret_cast<uint2*>(&Pl[pbase + mi * 16 + kg * 4]) =
          *reinterpret_cast<const uint2*>(w);
    }

    __syncthreads();  // MIDBAR: Vt(c) visible to all waves before PV

    // 7. O^T += V^T . P^T : 2 key-chunks x 5 d-tiles
    __builtin_amdgcn_s_setprio(1);
#pragma unroll
    for (int kc = 0; kc < 2; ++kc) {
      short8 pb = *reinterpret_cast<const short8*>(&Pl[pbase + kc * 32 + kg * 8]);
#pragma unroll
      for (int dt = 0; dt < 5; ++dt) {
        const int d = dt * 16 + lm;
        short8 va = *reinterpret_cast<const short8*>(
            &Vt[d * VSTR + ((kc * 32 + kg * 8) ^ (((d >> 3) & 7) << 3))]);
        oacc[dt] = __builtin_amdgcn_mfma_f32_16x16x32_bf16(va, pb, oacc[dt], 0, 0, 0);
      }
    }
    __builtin_amdgcn_s_setprio(0);

    __syncthreads();  // ENDBAR: PV(c) reads drained -> next commitV safe
  }

  // ---- epilogue: O^T frag col=q=lm, row=d=dt*16+kg*4+r; bf16 out ----
  if (qrow < s1) {
    const float inv = 1.f / l;
    bf16* op = out + (size_t)qrow * DIM + h * HD;
#pragma unroll
    for (int dt = 0; dt < 5; ++dt) {
      __align__(8) bf16 w[4] = {f2b(oacc[dt][0] * inv), f2b(oacc[dt][1] * inv),
                                f2b(oacc[dt][2] * inv), f2b(oacc[dt][3] * inv)};
      *reinterpret_cast<uint2*>(op + dt * 16 + kg * 4) =
          *reinterpret_cast<const uint2*>(w);
    }
  }
}

// ---------------------------------------------------------------------------
extern "C" void kernel_launch(void* const* d_in, const int* in_sizes, int n_in,
                              void* d_out, int out_size, void* d_ws, size_t ws_size,
                              hipStream_t stream) {
  const float* hs    = (const float*)d_in[0];
  const int*   cu    = (const int*)d_in[1];
  const float* cosb  = (const float*)d_in[2];
  const float* sinb  = (const float*)d_in[3];
  const float* Wqkv  = (const float*)d_in[4];
  const float* bqkv  = (const float*)d_in[5];
  const float* Wproj = (const float*)d_in[6];
  const float* bproj = (const float*)d_in[7];

  // ws: qkv bf16 15.73MB | attn_out bf16 5.24MB | WqkvT 9.83MB | WprojT 3.28MB
  //     | hs_bf16 5.24MB  = 39.3 MB
  bf16* qkv      = (bf16*)d_ws;
  bf16* attn_out = qkv + (size_t)N_TOK * QKV_N;
  bf16* WqkvT    = attn_out + (size_t)N_TOK * DIM;
  bf16* WprojT   = WqkvT + (size_t)QKV_N * DIM;
  bf16* hsb      = WprojT + (size_t)DIM * DIM;

  // 0) fused prep: cast hs + transpose both weights
  prep_kernel<<<dim3(QKV_N / 32, DIM / 32, 3), 256, 0, stream>>>(
      hs, hsb, Wqkv, WqkvT, Wproj, WprojT);

  // 1) qkv = bf16(hsb @ Wqkv + bqkv)
  mfma_gemm<1><<<dim3(QKV_N / 128, N_TOK / 128), 256, 0, stream>>>(
      hsb, WqkvT, bqkv, qkv, N_TOK, QKV_N, DIM);

  // 2) RoPE on q,k
  rope_kernel<<<(N_TOK * 2 * NHEAD * (HD / 2)) / 256, 256, 0, stream>>>(
      qkv, cosb, sinb);

  // 3) MFMA flash attention -> attn_out (bf16); 8 waves, QBLK=128
  int nseg = in_sizes[1] - 1;
  attn_mfma_kernel<<<dim3(N_TOK / 128, nseg, NHEAD), 512, 0, stream>>>(
      qkv, cu, attn_out);

  // 4) out = attn_out @ Wproj + bproj (fp32 out)
  mfma_gemm<0><<<dim3(DIM / 128, N_TOK / 128), 256, 0, stream>>>(
      attn_out, WprojT, bproj, d_out, N_TOK, DIM, DIM);
}